// Round 5
// baseline (2805.502 us; speedup 1.0000x reference)
//
#include <hip/hip_runtime.h>
#include <cstdint>
#include <cstddef>

typedef unsigned short u16;
typedef float f32x4 __attribute__((ext_vector_type(4)));
typedef short s16x8 __attribute__((ext_vector_type(8)));
typedef unsigned short u16x4 __attribute__((ext_vector_type(4)));
typedef __bf16 bf16x8 __attribute__((ext_vector_type(8)));

#define DEV static __device__ __forceinline__

DEV u16 f2bf(float f) {
  uint32_t x = __float_as_uint(f);
  return (u16)((x + 0x7fffu + ((x >> 16) & 1u)) >> 16);  // RNE
}
DEV float bf2f(u16 u) { return __uint_as_float(((uint32_t)u) << 16); }

DEV f32x4 mfma16(bf16x8 a, bf16x8 b, f32x4 c) {
  return __builtin_amdgcn_mfma_f32_16x16x32_bf16(a, b, c, 0, 0, 0);
}

DEV uint32_t pkbf(float lo, float hi) {
  uint32_t r;
  asm("v_cvt_pk_bf16_f32 %0, %1, %2" : "=v"(r) : "v"(lo), "v"(hi));
  return r;
}

// u16-index into a [128 rows][32 k] LDS tile (64B rows), XOR-swizzled on 16B slots.
// Both the staging ds_write_b128 (row=e>>2, slot=e&3) and the fragment ds_read_b128
// (rows base+l15, slot g) land exactly 8 lanes per 4-bank group = conflict-free.
DEV int swz32(int row, int slot8) { return row * 32 + (slot8 ^ ((row & 3) << 3)); }

// ---------------- copy x_cls -> d_out ----------------
__global__ __launch_bounds__(256) void k_copy(const float* __restrict__ src,
                                              float* __restrict__ dst, int n4) {
  int i = blockIdx.x * blockDim.x + threadIdx.x;
  const float4* s = (const float4*)src;
  float4* d = (float4*)dst;
  for (; i < n4; i += gridDim.x * blockDim.x) d[i] = s[i];
}

// ---------------- fp32 -> bf16 cast (proj/fc2 weights) ----------------
__global__ __launch_bounds__(256) void k_cast4(const float* __restrict__ src,
                                               u16* __restrict__ dst, int n4) {
  int i = blockIdx.x * blockDim.x + threadIdx.x;
  for (; i < n4; i += gridDim.x * blockDim.x) {
    float4 v = ((const float4*)src)[i];
    u16x4 o;
    o[0] = f2bf(v.x); o[1] = f2bf(v.y); o[2] = f2bf(v.z); o[3] = f2bf(v.w);
    ((u16x4*)dst)[i] = o;
  }
}

// ---------------- Weight fold: Wout = W .* lw (bf16); bout = b0 + W @ lb ----------------
__global__ __launch_bounds__(256) void k_fold(const float* __restrict__ W,
                                              const float* __restrict__ lw,
                                              const float* __restrict__ lb,
                                              const float* __restrict__ b0,
                                              u16* __restrict__ Wout,
                                              float* __restrict__ bout, int nrows) {
  int wv = blockIdx.x * 4 + (threadIdx.x >> 6), lane = threadIdx.x & 63;
  if (wv >= nrows) return;
  float4 w4 = ((const float4*)(W + (size_t)wv * 256))[lane];
  float4 s4 = ((const float4*)lw)[lane];
  float4 t4 = ((const float4*)lb)[lane];
  u16x4 o;
  o[0] = f2bf(w4.x * s4.x); o[1] = f2bf(w4.y * s4.y);
  o[2] = f2bf(w4.z * s4.z); o[3] = f2bf(w4.w * s4.w);
  ((u16x4*)(Wout + (size_t)wv * 256))[lane] = o;
  float d = w4.x * t4.x + w4.y * t4.y + w4.z * t4.z + w4.w * t4.w;
#pragma unroll
  for (int m = 1; m < 64; m <<= 1) d += __shfl_xor(d, m, 64);
  if (lane == 0) bout[wv] = (b0 ? b0[wv] : 0.f) + d;
}

// ---------------- Pure normalize (affine folded into weights); compact outputs ----------
__global__ __launch_bounds__(256) void k_norm(const float* __restrict__ src,
                                              u16* __restrict__ out, int ntok) {
  int wv = blockIdx.x * 4 + (threadIdx.x >> 6), lane = threadIdx.x & 63;
  if (wv >= ntok) return;
  float4 v = ((const float4*)(src + (size_t)wv * 256))[lane];
  float s = v.x + v.y + v.z + v.w;
  float q = v.x * v.x + v.y * v.y + v.z * v.z + v.w * v.w;
#pragma unroll
  for (int m = 1; m < 64; m <<= 1) {
    s += __shfl_xor(s, m, 64);
    q += __shfl_xor(q, m, 64);
  }
  float mean = s * (1.f / 256.f);
  float var = q * (1.f / 256.f) - mean * mean;
  float rstd = rsqrtf(var + 1e-5f);
  u16x4 o;
  o[0] = f2bf((v.x - mean) * rstd);
  o[1] = f2bf((v.y - mean) * rstd);
  o[2] = f2bf((v.z - mean) * rstd);
  o[3] = f2bf((v.w - mean) * rstd);
  ((u16x4*)(out + (size_t)wv * 256))[lane] = o;
}

// ---------------- MFMA GEMM: C[M,N] = A[M,K] @ Bw[N,K]^T + bias ----------------
// 128x128 tile, 4 waves, BK=32 (8+ ksteps), double-buffered LDS, depth-2 reg
// prefetch, 1 barrier/kstep. 1-D grid: by = bid & (nby-1), bx = bid >> lognby
// (n-siblings adjacent -> A panel L3/L2-shared). Requires N%128==0, K%64==0.
// rowmap: 0 = out row R=gm; 1 = patch (b=gm/2025, R=b*2100+75+rem);
//         2 = cls (b=gm/75, R=b*2100+rem)
// modes: 0 = kv plane store bf16: obf[((gn>>5)*134400 + R)*32 + (gn&31)]
//        1 = obf[gm*N+gn] = bf16(v*scale)   (R unused; rowmap=0)
//        2 = of32[gm*N+gn] += gamma[gn]*v
//        3 = obf[gm*N+gn] = bf16(gelu(v))
__global__ __launch_bounds__(256) void k_gemm4(const u16* __restrict__ A,
                                               const u16* __restrict__ Bw,
                                               int M, int N, int K, int mode, int rowmap,
                                               int lognby, float scale,
                                               const float* __restrict__ bias,
                                               const float* __restrict__ gamma,
                                               u16* __restrict__ obf,
                                               float* __restrict__ of32) {
  __shared__ __align__(16) u16 sA[2][4096];   // [128][32] u16, swizzled slots
  __shared__ __align__(16) u16 sB[2][4096];
  const int tid = threadIdx.x, lane = tid & 63, w = tid >> 6;
  const int l15 = lane & 15, g = lane >> 4;
  const int wm = w >> 1, wn = w & 1;
  const int bid = blockIdx.x;
  const int by = bid & ((1 << lognby) - 1), bx = bid >> lognby;
  const int m0 = bx * 128, n0 = by * 128;

  // staging geometry: chunk c: e = tid + 256c -> row=e>>2, slot=e&3 (16B each)
  const u16* aSrc[2];
  const u16* bSrc[2];
  int wOff[2];
#pragma unroll
  for (int c = 0; c < 2; c++) {
    int e = tid + 256 * c;
    int row = e >> 2, sl = e & 3;
    int am = m0 + row; if (am > M - 1) am = M - 1;
    aSrc[c] = A + (size_t)am * K + sl * 8;
    bSrc[c] = Bw + (size_t)(n0 + row) * K + sl * 8;
    wOff[c] = swz32(row, sl * 8);
  }

  f32x4 acc[4][4] = {};
  const int nkt = K >> 5;

  s16x8 rA[2][2], rB[2][2];
#pragma unroll
  for (int c = 0; c < 2; c++) {
    rA[0][c] = *(const s16x8*)aSrc[c];
    rB[0][c] = *(const s16x8*)bSrc[c];
    rA[1][c] = *(const s16x8*)(aSrc[c] + 32);
    rB[1][c] = *(const s16x8*)(bSrc[c] + 32);
  }
#pragma unroll
  for (int c = 0; c < 2; c++) {
    *(s16x8*)&sA[0][wOff[c]] = rA[0][c];
    *(s16x8*)&sB[0][wOff[c]] = rB[0][c];
  }
  asm volatile("s_waitcnt lgkmcnt(0)" ::: "memory");
  __builtin_amdgcn_s_barrier();
  __builtin_amdgcn_sched_barrier(0);

  int cur = 0;
  for (int kt = 0; kt < nkt; kt++) {
    const int ph = kt & 1;
    // fragments from buf[cur]
    s16x8 af[4], bfr[4];
#pragma unroll
    for (int i = 0; i < 4; i++) {
      int r = wm * 64 + i * 16 + l15;
      af[i] = *(const s16x8*)&sA[cur][swz32(r, g * 8)];
      int n = wn * 64 + i * 16 + l15;
      bfr[i] = *(const s16x8*)&sB[cur][swz32(n, g * 8)];
    }
    // stage tile kt+1 into buf[cur^1] (regs were loaded 2 steps ago)
    if (kt + 1 < nkt) {
#pragma unroll
      for (int c = 0; c < 2; c++) {
        *(s16x8*)&sA[cur ^ 1][wOff[c]] = rA[ph ^ 1][c];
        *(s16x8*)&sB[cur ^ 1][wOff[c]] = rB[ph ^ 1][c];
      }
    }
    // issue loads for tile kt+2 (budget: ~2 ksteps of compute)
    if (kt + 2 < nkt) {
      int ko = (kt + 2) << 5;
#pragma unroll
      for (int c = 0; c < 2; c++) {
        rA[ph][c] = *(const s16x8*)(aSrc[c] + ko);
        rB[ph][c] = *(const s16x8*)(bSrc[c] + ko);
      }
    }
#pragma unroll
    for (int i = 0; i < 4; i++)
#pragma unroll
      for (int j = 0; j < 4; j++)
        acc[i][j] = mfma16(__builtin_bit_cast(bf16x8, af[i]),
                           __builtin_bit_cast(bf16x8, bfr[j]), acc[i][j]);
    asm volatile("s_waitcnt lgkmcnt(0)" ::: "memory");
    __builtin_amdgcn_s_barrier();
    __builtin_amdgcn_sched_barrier(0);
    cur ^= 1;
  }

#pragma unroll
  for (int i = 0; i < 4; i++) {
#pragma unroll
    for (int j = 0; j < 4; j++) {
      int gmBase = m0 + wm * 64 + i * 16 + g * 4;
      int gn = n0 + wn * 64 + j * 16 + l15;
      float bs = bias[gn];
#pragma unroll
      for (int r = 0; r < 4; r++) {
        int gm = gmBase + r;
        if (gm >= M) continue;
        float v = acc[i][j][r] + bs;
        if (mode == 0) {
          int R;
          if (rowmap == 1) {
            uint32_t b = (uint32_t)(((uint64_t)(uint32_t)gm * 2121719ull) >> 32);
            R = (int)b * 2100 + 75 + (gm - (int)b * 2025);
          } else if (rowmap == 2) {
            uint32_t b = (uint32_t)(((uint64_t)(uint32_t)gm * 57266231ull) >> 32);
            R = (int)b * 2100 + (gm - (int)b * 75);
          } else {
            R = gm;
          }
          obf[((size_t)(gn >> 5) * 134400 + R) * 32 + (gn & 31)] = f2bf(v);
        } else if (mode == 1) {
          obf[(size_t)gm * N + gn] = f2bf(v * scale);
        } else if (mode == 2) {
          of32[(size_t)gm * N + gn] += gamma[gn] * v;
        } else {
          obf[(size_t)gm * N + gn] = f2bf(0.5f * v * (1.f + erff(v * 0.70710678118654752f)));
        }
      }
    }
  }
}

// ---------------- MFMA flash attention (R2-proven) ----------------
__global__ __launch_bounds__(256) void k_attn(const u16* __restrict__ qb,
                                              const u16* __restrict__ kvb,
                                              u16* __restrict__ obf) {
  __shared__ u16 VtS[4][32][36];
  __shared__ uint32_t Pbuf[4][16][20];
  __shared__ float maccS[4][2560];
  __shared__ float mlS[4][160];

  const int bid = blockIdx.x;
  const int b = bid & 63, h = bid >> 6;
  const int tid = threadIdx.x, lane = tid & 63, w = tid >> 6;
  const int l15 = lane & 15, g = lane >> 4;

  const u16* Kp = kvb + ((size_t)h * 134400 + (size_t)b * 2100) * 32;
  const u16* Vp = kvb + ((size_t)(8 + h) * 134400 + (size_t)b * 2100) * 32;

  bf16x8 bq[5];
#pragma unroll
  for (int qt = 0; qt < 5; qt++) {
    int q = qt * 16 + l15; if (q > 74) q = 74;
    s16x8 qv = *(const s16x8*)(qb + (size_t)(b * 75 + q) * 256 + h * 32 + g * 8);
    bq[qt] = __builtin_bit_cast(bf16x8, qv);
  }

  f32x4 acc[5][2] = {};
  float mlc[5], llc[5];
#pragma unroll
  for (int qt = 0; qt < 5; qt++) { mlc[qt] = -1e30f; llc[qt] = 0.f; }

  s16x8 kfA, kfB, vvA, vvB;
  {
    int t0 = w * 32;
    int ta = t0 + l15; if (ta > 2099) ta = 2099;
    int tb = t0 + 16 + l15; if (tb > 2099) tb = 2099;
    kfA = *(const s16x8*)(Kp + (size_t)ta * 32 + g * 8);
    kfB = *(const s16x8*)(Kp + (size_t)tb * 32 + g * 8);
    int tga = t0 + (lane >> 2); if (tga > 2099) tga = 2099;
    int tgb = t0 + ((lane + 64) >> 2); if (tgb > 2099) tgb = 2099;
    vvA = *(const s16x8*)(Vp + (size_t)tga * 32 + (lane & 3) * 8);
    vvB = *(const s16x8*)(Vp + (size_t)tgb * 32 + (lane & 3) * 8);
  }

  for (int tt = w; tt < 66; tt += 4) {
    const int t0 = tt * 32;
    {
      u16* d0 = &VtS[w][lane >> 2][(lane & 3) * 8];
      u16* d1 = &VtS[w][(lane + 64) >> 2][(lane & 3) * 8];
#pragma unroll
      for (int e = 0; e < 8; e++) d0[e] = (u16)vvA[e];
#pragma unroll
      for (int e = 0; e < 8; e++) d1[e] = (u16)vvB[e];
    }
    bf16x8 bA = __builtin_bit_cast(bf16x8, kfA);
    bf16x8 bB = __builtin_bit_cast(bf16x8, kfB);
    s16x8 v0, v1;
#pragma unroll
    for (int e = 0; e < 8; e++) {
      v0[e] = (short)VtS[w][8 * g + e][l15];
      v1[e] = (short)VtS[w][8 * g + e][16 + l15];
    }
    bf16x8 bv0 = __builtin_bit_cast(bf16x8, v0);
    bf16x8 bv1 = __builtin_bit_cast(bf16x8, v1);
    int tn = tt + 4;
    if (tn < 66) {
      int t0n = tn * 32;
      int ta = t0n + l15; if (ta > 2099) ta = 2099;
      int tb = t0n + 16 + l15; if (tb > 2099) tb = 2099;
      kfA = *(const s16x8*)(Kp + (size_t)ta * 32 + g * 8);
      kfB = *(const s16x8*)(Kp + (size_t)tb * 32 + g * 8);
      int tga = t0n + (lane >> 2); if (tga > 2099) tga = 2099;
      int tgb = t0n + ((lane + 64) >> 2); if (tgb > 2099) tgb = 2099;
      vvA = *(const s16x8*)(Vp + (size_t)tga * 32 + (lane & 3) * 8);
      vvB = *(const s16x8*)(Vp + (size_t)tgb * 32 + (lane & 3) * 8);
    }
    const bool lastTile = (t0 == 2080);

#pragma unroll
    for (int qt = 0; qt < 5; qt++) {
      f32x4 z = {0.f, 0.f, 0.f, 0.f};
      f32x4 sA = mfma16(bA, bq[qt], z);
      f32x4 sB = mfma16(bB, bq[qt], z);
      if (lastTile && g >= 1) {
        sB[0] = sB[1] = sB[2] = sB[3] = -1e30f;
      }
      float px = fmaxf(fmaxf(fmaxf(sA[0], sA[1]), fmaxf(sA[2], sA[3])),
                       fmaxf(fmaxf(sB[0], sB[1]), fmaxf(sB[2], sB[3])));
      px = fmaxf(px, __shfl_xor(px, 16, 64));
      px = fmaxf(px, __shfl_xor(px, 32, 64));
      float mq = mlc[qt];
      if (!__all(px <= mq + 8.f)) {
        float mn = fmaxf(mq, px);
        float rs = exp2f(mq - mn);
        mlc[qt] = mn;
        llc[qt] *= rs;
#pragma unroll
        for (int r = 0; r < 4; r++) {
          float rr = __shfl(rs, ((lane >> 4) << 2) + r, 64);
          acc[qt][0][r] *= rr;
          acc[qt][1][r] *= rr;
        }
        mq = mn;
      }
      f32x4 pA, pB;
#pragma unroll
      for (int r = 0; r < 4; r++) {
        pA[r] = exp2f(sA[r] - mq);
        pB[r] = exp2f(sB[r] - mq);
      }
      float ps = pA[0] + pA[1] + pA[2] + pA[3] + pB[0] + pB[1] + pB[2] + pB[3];
      ps += __shfl_xor(ps, 16, 64);
      ps += __shfl_xor(ps, 32, 64);
      llc[qt] += ps;
      uint32_t* Pu = &Pbuf[w][l15][0];
      Pu[2 * g]     = pkbf(pA[0], pA[1]);
      Pu[2 * g + 1] = pkbf(pA[2], pA[3]);
      Pu[8 + 2 * g]     = pkbf(pB[0], pB[1]);
      Pu[8 + 2 * g + 1] = pkbf(pB[2], pB[3]);
      uint4 pu = *(const uint4*)&Pbuf[w][l15][4 * g];
      bf16x8 bp = __builtin_bit_cast(bf16x8, pu);
      acc[qt][0] = mfma16(bp, bv0, acc[qt][0]);
      acc[qt][1] = mfma16(bp, bv1, acc[qt][1]);
    }
  }

#pragma unroll
  for (int qt = 0; qt < 5; qt++)
#pragma unroll
    for (int dh = 0; dh < 2; dh++)
#pragma unroll
      for (int r = 0; r < 4; r++) {
        int q = qt * 16 + 4 * g + r;
        maccS[w][q * 32 + dh * 16 + l15] = acc[qt][dh][r];
      }
  if (lane < 16) {
#pragma unroll
    for (int qt = 0; qt < 5; qt++) {
      mlS[w][qt * 16 + l15] = mlc[qt];
      mlS[w][80 + qt * 16 + l15] = llc[qt];
    }
  }
  __syncthreads();

  for (int idx = tid; idx < 2400; idx += 256) {
    int q = idx >> 5, d = idx & 31;
    float M = -1e30f;
#pragma unroll
    for (int ww = 0; ww < 4; ww++) M = fmaxf(M, mlS[ww][q]);
    float L = 0.f, O = 0.f;
#pragma unroll
    for (int ww = 0; ww < 4; ww++) {
      float sc = exp2f(mlS[ww][q] - M);
      L += mlS[ww][80 + q] * sc;
      O += maccS[ww][q * 32 + d] * sc;
    }
    obf[(size_t)(b * 75 + q) * 256 + h * 32 + d] = f2bf(O / L);
  }
}

// ---------------- host ----------------
extern "C" void kernel_launch(void* const* d_in, const int* in_sizes, int n_in,
                              void* d_out, int out_size, void* d_ws, size_t ws_size,
                              hipStream_t stream) {
  const float* x_cls   = (const float*)d_in[0];
  const float* x_patch = (const float*)d_in[1];
  const float* ln1_w   = (const float*)d_in[2];
  const float* ln1_b   = (const float*)d_in[3];
  const float* q_w     = (const float*)d_in[4];
  const float* k_w     = (const float*)d_in[5];
  const float* v_w     = (const float*)d_in[6];
  const float* proj_w  = (const float*)d_in[7];
  const float* proj_b  = (const float*)d_in[8];
  const float* ln2_w   = (const float*)d_in[9];
  const float* ln2_b   = (const float*)d_in[10];
  const float* fc1_w   = (const float*)d_in[11];
  const float* fc1_b   = (const float*)d_in[12];
  const float* fc2_w   = (const float*)d_in[13];
  const float* fc2_b   = (const float*)d_in[14];
  const float* gamma1  = (const float*)d_in[15];
  const float* gamma2  = (const float*)d_in[16];
  float* xc = (float*)d_out;

  char* ws = (char*)d_ws;
  size_t off = 0;
  auto alloc = [&](size_t bytes) {
    char* p = ws + off;
    off += (bytes + 255) & ~(size_t)255;
    return p;
  };
  u16* nxp   = (u16*)alloc(129600ull * 256 * 2);  // normalized patches, b-major compact
  u16* uncls = (u16*)alloc(4800ull * 256 * 2);    // normalized cls tokens
  u16* kvb   = (u16*)alloc(134400ull * 512 * 2);  // 16 planes [134400][32]
  u16* qb    = (u16*)alloc(4800ull * 256 * 2);
  u16* ob    = (u16*)alloc(4800ull * 256 * 2);
  u16* xn    = (u16*)alloc(4800ull * 256 * 2);
  u16* hb    = (u16*)alloc(4800ull * 1024 * 2);
  u16* qp    = (u16*)alloc(2ull * 65536 * 2);
  u16* kvp   = (u16*)alloc(2ull * 131072 * 2);
  u16* pjp   = (u16*)alloc(2ull * 65536 * 2);
  u16* f1p   = (u16*)alloc(2ull * 262144 * 2);
  u16* f2p   = (u16*)alloc(2ull * 262144 * 2);
  float* bias_kv = (float*)alloc(2ull * 512 * 4);
  float* bias_q  = (float*)alloc(2ull * 256 * 4);
  float* bias_f1 = (float*)alloc(2ull * 1024 * 4);

  k_copy<<<1200, 256, 0, stream>>>(x_cls, xc, 307200);
  for (int i = 0; i < 2; i++) {
    k_fold<<<64, 256, 0, stream>>>(k_w + i * 65536, ln1_w + i * 256, ln1_b + i * 256,
                                   nullptr, kvp + i * 131072, bias_kv + i * 512, 256);
    k_fold<<<64, 256, 0, stream>>>(v_w + i * 65536, ln1_w + i * 256, ln1_b + i * 256,
                                   nullptr, kvp + i * 131072 + 65536, bias_kv + i * 512 + 256, 256);
    k_fold<<<64, 256, 0, stream>>>(q_w + i * 65536, ln1_w + i * 256, ln1_b + i * 256,
                                   nullptr, qp + i * 65536, bias_q + i * 256, 256);
    k_fold<<<256, 256, 0, stream>>>(fc1_w + i * 262144, ln2_w + i * 256, ln2_b + i * 256,
                                    fc1_b + i * 1024, f1p + i * 262144, bias_f1 + i * 1024, 1024);
    k_cast4<<<64, 256, 0, stream>>>(proj_w + i * 65536, pjp + i * 65536, 16384);
    k_cast4<<<256, 256, 0, stream>>>(fc2_w + i * 262144, f2p + i * 262144, 65536);
  }
  // normalize patch tokens ONCE (identical across both CA blocks)
  k_norm<<<32400, 256, 0, stream>>>(x_patch, nxp, 129600);

  const float qscale = 0.25503489f;  // 1/sqrt(32) * log2(e)
  for (int i = 0; i < 2; i++) {
    k_norm<<<1200, 256, 0, stream>>>(xc, uncls, 4800);
    // patch K/V -> kvb planes (rowmap 1)
    k_gemm4<<<1013 * 4, 256, 0, stream>>>(nxp, kvp + i * 131072, 129600, 512, 256,
                                          0, 1, 2, 0.f, bias_kv + i * 512, nullptr,
                                          kvb, nullptr);
    // cls K/V -> kvb planes (rowmap 2)
    k_gemm4<<<38 * 4, 256, 0, stream>>>(uncls, kvp + i * 131072, 4800, 512, 256,
                                        0, 2, 2, 0.f, bias_kv + i * 512, nullptr,
                                        kvb, nullptr);
    k_gemm4<<<38 * 2, 256, 0, stream>>>(uncls, qp + i * 65536, 4800, 256, 256,
                                        1, 0, 1, qscale, bias_q + i * 256, nullptr,
                                        qb, nullptr);
    k_attn<<<512, 256, 0, stream>>>(qb, kvb, ob);
    k_gemm4<<<38 * 2, 256, 0, stream>>>(ob, pjp + i * 65536, 4800, 256, 256,
                                        2, 0, 1, 0.f, proj_b + i * 256, gamma1 + i * 256,
                                        nullptr, xc);
    k_norm<<<1200, 256, 0, stream>>>(xc, xn, 4800);
    k_gemm4<<<38 * 8, 256, 0, stream>>>(xn, f1p + i * 262144, 4800, 1024, 256,
                                        3, 0, 3, 0.f, bias_f1 + i * 1024, nullptr,
                                        hb, nullptr);
    k_gemm4<<<38 * 2, 256, 0, stream>>>(hb, f2p + i * 262144, 4800, 256, 1024,
                                        2, 0, 1, 0.f, fc2_b + i * 256, gamma2 + i * 256,
                                        nullptr, xc);
  }
}

// Round 6
// 692.637 us; speedup vs baseline: 4.0505x; 4.0505x over previous
//
#include <hip/hip_runtime.h>
#include <cstdint>
#include <cstddef>

typedef unsigned short u16;
typedef float f32x4 __attribute__((ext_vector_type(4)));
typedef short s16x8 __attribute__((ext_vector_type(8)));
typedef unsigned short u16x4 __attribute__((ext_vector_type(4)));
typedef __bf16 bf16x8 __attribute__((ext_vector_type(8)));

#define DEV static __device__ __forceinline__

DEV u16 f2bf(float f) {
  uint32_t x = __float_as_uint(f);
  return (u16)((x + 0x7fffu + ((x >> 16) & 1u)) >> 16);  // RNE
}
DEV float bf2f(u16 u) { return __uint_as_float(((uint32_t)u) << 16); }

DEV f32x4 mfma16(bf16x8 a, bf16x8 b, f32x4 c) {
  return __builtin_amdgcn_mfma_f32_16x16x32_bf16(a, b, c, 0, 0, 0);
}

DEV void mfma_bf16_asm(f32x4& acc, s16x8 a, s16x8 b) {
  asm volatile("v_mfma_f32_16x16x32_bf16 %0, %1, %2, %0" : "+v"(acc) : "v"(a), "v"(b));
}

DEV uint32_t pkbf(float lo, float hi) {
  uint32_t r;
  asm("v_cvt_pk_bf16_f32 %0, %1, %2" : "=v"(r) : "v"(lo), "v"(hi));
  return r;
}

DEV int swz(int b) { return b ^ ((b >> 2) & 0x70); }  // R2-proven byte swizzle

// ---------------- copy x_cls -> d_out ----------------
__global__ __launch_bounds__(256) void k_copy(const float* __restrict__ src,
                                              float* __restrict__ dst, int n4) {
  int i = blockIdx.x * blockDim.x + threadIdx.x;
  const float4* s = (const float4*)src;
  float4* d = (float4*)dst;
  for (; i < n4; i += gridDim.x * blockDim.x) d[i] = s[i];
}

// ---------------- fp32 -> bf16 cast (proj/fc2 weights) ----------------
__global__ __launch_bounds__(256) void k_cast4(const float* __restrict__ src,
                                               u16* __restrict__ dst, int n4) {
  int i = blockIdx.x * blockDim.x + threadIdx.x;
  for (; i < n4; i += gridDim.x * blockDim.x) {
    float4 v = ((const float4*)src)[i];
    u16x4 o;
    o[0] = f2bf(v.x); o[1] = f2bf(v.y); o[2] = f2bf(v.z); o[3] = f2bf(v.w);
    ((u16x4*)dst)[i] = o;
  }
}

// ---------------- Weight fold: Wout = W .* lw (bf16); bout = b0 + W @ lb ----------------
__global__ __launch_bounds__(256) void k_fold(const float* __restrict__ W,
                                              const float* __restrict__ lw,
                                              const float* __restrict__ lb,
                                              const float* __restrict__ b0,
                                              u16* __restrict__ Wout,
                                              float* __restrict__ bout, int nrows) {
  int wv = blockIdx.x * 4 + (threadIdx.x >> 6), lane = threadIdx.x & 63;
  if (wv >= nrows) return;
  float4 w4 = ((const float4*)(W + (size_t)wv * 256))[lane];
  float4 s4 = ((const float4*)lw)[lane];
  float4 t4 = ((const float4*)lb)[lane];
  u16x4 o;
  o[0] = f2bf(w4.x * s4.x); o[1] = f2bf(w4.y * s4.y);
  o[2] = f2bf(w4.z * s4.z); o[3] = f2bf(w4.w * s4.w);
  ((u16x4*)(Wout + (size_t)wv * 256))[lane] = o;
  float d = w4.x * t4.x + w4.y * t4.y + w4.z * t4.z + w4.w * t4.w;
#pragma unroll
  for (int m = 1; m < 64; m <<= 1) d += __shfl_xor(d, m, 64);
  if (lane == 0) bout[wv] = (b0 ? b0[wv] : 0.f) + d;
}

// ---------------- Pure normalize (affine folded into weights); compact out ----------
__global__ __launch_bounds__(256) void k_norm(const float* __restrict__ src,
                                              u16* __restrict__ out, int ntok) {
  int wv = blockIdx.x * 4 + (threadIdx.x >> 6), lane = threadIdx.x & 63;
  if (wv >= ntok) return;
  float4 v = ((const float4*)(src + (size_t)wv * 256))[lane];
  float s = v.x + v.y + v.z + v.w;
  float q = v.x * v.x + v.y * v.y + v.z * v.z + v.w * v.w;
#pragma unroll
  for (int m = 1; m < 64; m <<= 1) {
    s += __shfl_xor(s, m, 64);
    q += __shfl_xor(q, m, 64);
  }
  float mean = s * (1.f / 256.f);
  float var = q * (1.f / 256.f) - mean * mean;
  float rstd = rsqrtf(var + 1e-5f);
  u16x4 o;
  o[0] = f2bf((v.x - mean) * rstd);
  o[1] = f2bf((v.y - mean) * rstd);
  o[2] = f2bf((v.z - mean) * rstd);
  o[3] = f2bf((v.w - mean) * rstd);
  ((u16x4*)(out + (size_t)wv * 256))[lane] = o;
}

// ---------------- MFMA GEMM (R2-proven loop + rowmap/bias epilogue) ----------------
// C[M,N] = A[M,K] @ Bw[N,K]^T + bias. 128x128 tile, 4 waves, BK=32, single-buf
// LDS, __syncthreads barriers, compiler-scheduled loads (occupancy = pipeline).
// 1-D grid: by = bid & (2^lognby - 1) (n-siblings adjacent for A-panel L2 reuse).
// rowmap: 0 = R=gm; 1 = patch (b=gm/2025, R=b*2100+75+rem); 2 = cls (b=gm/75, R=b*2100+rem)
// modes: 0 = kv plane store: obf[((gn>>5)*134400 + R)*32 + (gn&31)]
//        1 = obf[gm*N+gn] = bf16(v*scale)
//        2 = of32[gm*N+gn] += gamma[gn]*v
//        3 = obf[gm*N+gn] = bf16(gelu(v))
__global__ __launch_bounds__(256) void k_gemm5(const u16* __restrict__ A,
                                               const u16* __restrict__ Bw,
                                               int M, int N, int K, int mode, int rowmap,
                                               int lognby, float scale,
                                               const float* __restrict__ bias,
                                               const float* __restrict__ gamma,
                                               u16* __restrict__ obf,
                                               float* __restrict__ of32) {
  __shared__ __align__(16) char smA[8192];
  __shared__ __align__(16) char smB[8192];
  const int tid = threadIdx.x;
  const int lane = tid & 63, wid = tid >> 6;
  const int wm = wid >> 1, wn = wid & 1;
  const int bid = blockIdx.x;
  const int by = bid & ((1 << lognby) - 1), bx = bid >> lognby;
  const int m0 = bx * 128, n0 = by * 128;
  const int g = lane >> 4, l15 = lane & 15;

  f32x4 acc[4][4] = {};

  for (int k0 = 0; k0 < K; k0 += 32) {
#pragma unroll
    for (int c = 0; c < 2; c++) {
      int e = tid + c * 256;
      int row = e >> 2, seg = e & 3;
      int am = m0 + row;
      if (am > M - 1) am = M - 1;
      s16x8 av = *(const s16x8*)(A + (size_t)am * K + k0 + seg * 8);
      *(s16x8*)(smA + swz(e * 16)) = av;
      s16x8 bv = *(const s16x8*)(Bw + (size_t)(n0 + row) * K + k0 + seg * 8);
      *(s16x8*)(smB + swz(e * 16)) = bv;
    }
    __syncthreads();
    s16x8 af[4], bfr[4];
#pragma unroll
    for (int i = 0; i < 4; i++) {
      int lm = wm * 64 + i * 16 + l15;
      af[i] = *(const s16x8*)(smA + swz(lm * 64 + g * 16));
      int ln = wn * 64 + i * 16 + l15;
      bfr[i] = *(const s16x8*)(smB + swz(ln * 64 + g * 16));
    }
#pragma unroll
    for (int i = 0; i < 4; i++)
#pragma unroll
      for (int j = 0; j < 4; j++) mfma_bf16_asm(acc[i][j], af[i], bfr[j]);
    __syncthreads();
  }
  asm volatile("s_nop 7\n\ts_nop 7" ::: "memory");  // MFMA -> VALU hazard guard

#pragma unroll
  for (int i = 0; i < 4; i++) {
#pragma unroll
    for (int j = 0; j < 4; j++) {
      int gmBase = m0 + wm * 64 + i * 16 + g * 4;
      int gn = n0 + wn * 64 + j * 16 + l15;
      float bs = bias[gn];
#pragma unroll
      for (int r = 0; r < 4; r++) {
        int gm = gmBase + r;
        if (gm >= M) continue;
        float v = acc[i][j][r] + bs;
        if (mode == 0) {
          int R;
          if (rowmap == 1) {
            uint32_t b = (uint32_t)(((uint64_t)(uint32_t)gm * 2121719ull) >> 32);
            R = (int)b * 2100 + 75 + (gm - (int)b * 2025);
          } else if (rowmap == 2) {
            uint32_t b = (uint32_t)(((uint64_t)(uint32_t)gm * 57266231ull) >> 32);
            R = (int)b * 2100 + (gm - (int)b * 75);
          } else {
            R = gm;
          }
          obf[((size_t)(gn >> 5) * 134400 + R) * 32 + (gn & 31)] = f2bf(v);
        } else if (mode == 1) {
          obf[(size_t)gm * N + gn] = f2bf(v * scale);
        } else if (mode == 2) {
          of32[(size_t)gm * N + gn] += gamma[gn] * v;
        } else {
          obf[(size_t)gm * N + gn] = f2bf(0.5f * v * (1.f + erff(v * 0.70710678118654752f)));
        }
      }
    }
  }
}

// ---------------- MFMA flash attention, token-split (2 halves) ----------------
// grid 1024: b = bid&63, h = (bid>>6)&7, half = bid>>9. Each block does 33 of the
// 66 K/V tiles; writes f32 partials (O, m, l) in exp2 domain; k_acomb merges.
__global__ __launch_bounds__(256) void k_attn(const u16* __restrict__ qb,
                                              const u16* __restrict__ kvb,
                                              float* __restrict__ pO,
                                              float* __restrict__ pml) {
  __shared__ u16 VtS[4][32][36];
  __shared__ uint32_t Pbuf[4][16][20];
  __shared__ float maccS[4][2560];
  __shared__ float mlS[4][160];

  const int bid = blockIdx.x;
  const int b = bid & 63, h = (bid >> 6) & 7, half = bid >> 9;
  const int tid = threadIdx.x, lane = tid & 63, w = tid >> 6;
  const int l15 = lane & 15, g = lane >> 4;
  const int tbase = half * 33, tend = tbase + 33;

  const u16* Kp = kvb + ((size_t)h * 134400 + (size_t)b * 2100) * 32;
  const u16* Vp = kvb + ((size_t)(8 + h) * 134400 + (size_t)b * 2100) * 32;

  bf16x8 bq[5];
#pragma unroll
  for (int qt = 0; qt < 5; qt++) {
    int q = qt * 16 + l15; if (q > 74) q = 74;
    s16x8 qv = *(const s16x8*)(qb + (size_t)(b * 75 + q) * 256 + h * 32 + g * 8);
    bq[qt] = __builtin_bit_cast(bf16x8, qv);
  }

  f32x4 acc[5][2] = {};
  float mlc[5], llc[5];
#pragma unroll
  for (int qt = 0; qt < 5; qt++) { mlc[qt] = -1e30f; llc[qt] = 0.f; }

  s16x8 kfA, kfB, vvA, vvB;
  {
    int t0 = (tbase + w) * 32;
    int ta = t0 + l15; if (ta > 2099) ta = 2099;
    int tb = t0 + 16 + l15; if (tb > 2099) tb = 2099;
    kfA = *(const s16x8*)(Kp + (size_t)ta * 32 + g * 8);
    kfB = *(const s16x8*)(Kp + (size_t)tb * 32 + g * 8);
    int tga = t0 + (lane >> 2); if (tga > 2099) tga = 2099;
    int tgb = t0 + ((lane + 64) >> 2); if (tgb > 2099) tgb = 2099;
    vvA = *(const s16x8*)(Vp + (size_t)tga * 32 + (lane & 3) * 8);
    vvB = *(const s16x8*)(Vp + (size_t)tgb * 32 + (lane & 3) * 8);
  }

  for (int tt = tbase + w; tt < tend; tt += 4) {
    const int t0 = tt * 32;
    {
      u16* d0 = &VtS[w][lane >> 2][(lane & 3) * 8];
      u16* d1 = &VtS[w][(lane + 64) >> 2][(lane & 3) * 8];
#pragma unroll
      for (int e = 0; e < 8; e++) d0[e] = (u16)vvA[e];
#pragma unroll
      for (int e = 0; e < 8; e++) d1[e] = (u16)vvB[e];
    }
    bf16x8 bA = __builtin_bit_cast(bf16x8, kfA);
    bf16x8 bB = __builtin_bit_cast(bf16x8, kfB);
    s16x8 v0, v1;
#pragma unroll
    for (int e = 0; e < 8; e++) {
      v0[e] = (short)VtS[w][8 * g + e][l15];
      v1[e] = (short)VtS[w][8 * g + e][16 + l15];
    }
    bf16x8 bv0 = __builtin_bit_cast(bf16x8, v0);
    bf16x8 bv1 = __builtin_bit_cast(bf16x8, v1);
    int tn = tt + 4;
    if (tn < tend) {
      int t0n = tn * 32;
      int ta = t0n + l15; if (ta > 2099) ta = 2099;
      int tb = t0n + 16 + l15; if (tb > 2099) tb = 2099;
      kfA = *(const s16x8*)(Kp + (size_t)ta * 32 + g * 8);
      kfB = *(const s16x8*)(Kp + (size_t)tb * 32 + g * 8);
      int tga = t0n + (lane >> 2); if (tga > 2099) tga = 2099;
      int tgb = t0n + ((lane + 64) >> 2); if (tgb > 2099) tgb = 2099;
      vvA = *(const s16x8*)(Vp + (size_t)tga * 32 + (lane & 3) * 8);
      vvB = *(const s16x8*)(Vp + (size_t)tgb * 32 + (lane & 3) * 8);
    }
    const bool lastTile = (t0 == 2080);

#pragma unroll
    for (int qt = 0; qt < 5; qt++) {
      f32x4 z = {0.f, 0.f, 0.f, 0.f};
      f32x4 sA = mfma16(bA, bq[qt], z);
      f32x4 sB = mfma16(bB, bq[qt], z);
      if (lastTile && g >= 1) {
        sB[0] = sB[1] = sB[2] = sB[3] = -1e30f;
      }
      float px = fmaxf(fmaxf(fmaxf(sA[0], sA[1]), fmaxf(sA[2], sA[3])),
                       fmaxf(fmaxf(sB[0], sB[1]), fmaxf(sB[2], sB[3])));
      px = fmaxf(px, __shfl_xor(px, 16, 64));
      px = fmaxf(px, __shfl_xor(px, 32, 64));
      float mq = mlc[qt];
      if (!__all(px <= mq + 8.f)) {
        float mn = fmaxf(mq, px);
        float rs = exp2f(mq - mn);
        mlc[qt] = mn;
        llc[qt] *= rs;
#pragma unroll
        for (int r = 0; r < 4; r++) {
          float rr = __shfl(rs, ((lane >> 4) << 2) + r, 64);
          acc[qt][0][r] *= rr;
          acc[qt][1][r] *= rr;
        }
        mq = mn;
      }
      f32x4 pA, pB;
#pragma unroll
      for (int r = 0; r < 4; r++) {
        pA[r] = exp2f(sA[r] - mq);
        pB[r] = exp2f(sB[r] - mq);
      }
      float ps = pA[0] + pA[1] + pA[2] + pA[3] + pB[0] + pB[1] + pB[2] + pB[3];
      ps += __shfl_xor(ps, 16, 64);
      ps += __shfl_xor(ps, 32, 64);
      llc[qt] += ps;
      uint32_t* Pu = &Pbuf[w][l15][0];
      Pu[2 * g]     = pkbf(pA[0], pA[1]);
      Pu[2 * g + 1] = pkbf(pA[2], pA[3]);
      Pu[8 + 2 * g]     = pkbf(pB[0], pB[1]);
      Pu[8 + 2 * g + 1] = pkbf(pB[2], pB[3]);
      uint4 pu = *(const uint4*)&Pbuf[w][l15][4 * g];
      bf16x8 bp = __builtin_bit_cast(bf16x8, pu);
      acc[qt][0] = mfma16(bp, bv0, acc[qt][0]);
      acc[qt][1] = mfma16(bp, bv1, acc[qt][1]);
    }
  }

#pragma unroll
  for (int qt = 0; qt < 5; qt++)
#pragma unroll
    for (int dh = 0; dh < 2; dh++)
#pragma unroll
      for (int r = 0; r < 4; r++) {
        int q = qt * 16 + 4 * g + r;
        maccS[w][q * 32 + dh * 16 + l15] = acc[qt][dh][r];
      }
  if (lane < 16) {
#pragma unroll
    for (int qt = 0; qt < 5; qt++) {
      mlS[w][qt * 16 + l15] = mlc[qt];
      mlS[w][80 + qt * 16 + l15] = llc[qt];
    }
  }
  __syncthreads();

  // block-level combine of the 4 waves; write f32 partials
  if (tid < 75) {
    float M = -1e30f;
#pragma unroll
    for (int ww = 0; ww < 4; ww++) M = fmaxf(M, mlS[ww][tid]);
    float L = 0.f;
#pragma unroll
    for (int ww = 0; ww < 4; ww++) L += mlS[ww][80 + tid] * exp2f(mlS[ww][tid] - M);
    pml[(size_t)bid * 160 + tid] = M;
    pml[(size_t)bid * 160 + 80 + tid] = L;
  }
  for (int idx = tid; idx < 2400; idx += 256) {
    int q = idx >> 5;
    float M = -1e30f;
#pragma unroll
    for (int ww = 0; ww < 4; ww++) M = fmaxf(M, mlS[ww][q]);
    float O = 0.f;
#pragma unroll
    for (int ww = 0; ww < 4; ww++) O += maccS[ww][idx & 2559 ? idx : idx] * 0.f;  // placeholder avoided
    O = 0.f;
#pragma unroll
    for (int ww = 0; ww < 4; ww++) O += maccS[ww][idx] * exp2f(mlS[ww][q] - M);
    pO[(size_t)bid * 2400 + idx] = O;
  }
}

// ---------------- combine the two token-halves ----------------
__global__ __launch_bounds__(256) void k_acomb(const float* __restrict__ pO,
                                               const float* __restrict__ pml,
                                               u16* __restrict__ obf) {
  const int bid = blockIdx.x;  // 0..511 = (b,h)
  const int b = bid & 63, h = bid >> 6;
  const int tid = threadIdx.x;
  for (int idx = tid; idx < 2400; idx += 256) {
    int q = idx >> 5, d = idx & 31;
    float m0 = pml[(size_t)bid * 160 + q];
    float l0 = pml[(size_t)bid * 160 + 80 + q];
    float m1 = pml[(size_t)(bid + 512) * 160 + q];
    float l1 = pml[(size_t)(bid + 512) * 160 + 80 + q];
    float M = fmaxf(m0, m1);
    float s0 = exp2f(m0 - M), s1 = exp2f(m1 - M);
    float L = l0 * s0 + l1 * s1;
    float O = pO[(size_t)bid * 2400 + idx] * s0 + pO[(size_t)(bid + 512) * 2400 + idx] * s1;
    obf[(size_t)(b * 75 + q) * 256 + h * 32 + d] = f2bf(O / L);
  }
}

// ---------------- host ----------------
extern "C" void kernel_launch(void* const* d_in, const int* in_sizes, int n_in,
                              void* d_out, int out_size, void* d_ws, size_t ws_size,
                              hipStream_t stream) {
  const float* x_cls   = (const float*)d_in[0];
  const float* x_patch = (const float*)d_in[1];
  const float* ln1_w   = (const float*)d_in[2];
  const float* ln1_b   = (const float*)d_in[3];
  const float* q_w     = (const float*)d_in[4];
  const float* k_w     = (const float*)d_in[5];
  const float* v_w     = (const float*)d_in[6];
  const float* proj_w  = (const float*)d_in[7];
  const float* proj_b  = (const float*)d_in[8];
  const float* ln2_w   = (const float*)d_in[9];
  const float* ln2_b   = (const float*)d_in[10];
  const float* fc1_w   = (const float*)d_in[11];
  const float* fc1_b   = (const float*)d_in[12];
  const float* fc2_w   = (const float*)d_in[13];
  const float* fc2_b   = (const float*)d_in[14];
  const float* gamma1  = (const float*)d_in[15];
  const float* gamma2  = (const float*)d_in[16];
  float* xc = (float*)d_out;

  char* ws = (char*)d_ws;
  size_t off = 0;
  auto alloc = [&](size_t bytes) {
    char* p = ws + off;
    off += (bytes + 255) & ~(size_t)255;
    return p;
  };
  u16* nxp   = (u16*)alloc(129600ull * 256 * 2);  // normalized patches (both layers)
  u16* uncls = (u16*)alloc(4800ull * 256 * 2);    // normalized cls tokens
  u16* kvb   = (u16*)alloc(134400ull * 512 * 2);  // 16 planes [134400][32]
  u16* qb    = (u16*)alloc(4800ull * 256 * 2);
  u16* ob    = (u16*)alloc(4800ull * 256 * 2);
  u16* xn    = (u16*)alloc(4800ull * 256 * 2);
  u16* hb    = (u16*)alloc(4800ull * 1024 * 2);
  u16* qp    = (u16*)alloc(2ull * 65536 * 2);
  u16* kvp   = (u16*)alloc(2ull * 131072 * 2);
  u16* pjp   = (u16*)alloc(2ull * 65536 * 2);
  u16* f1p   = (u16*)alloc(2ull * 262144 * 2);
  u16* f2p   = (u16*)alloc(2ull * 262144 * 2);
  float* bias_kv = (float*)alloc(2ull * 512 * 4);
  float* bias_q  = (float*)alloc(2ull * 256 * 4);
  float* bias_f1 = (float*)alloc(2ull * 1024 * 4);
  float* pO  = (float*)alloc(1024ull * 2400 * 4);
  float* pml = (float*)alloc(1024ull * 160 * 4);

  k_copy<<<1200, 256, 0, stream>>>(x_cls, xc, 307200);
  for (int i = 0; i < 2; i++) {
    k_fold<<<64, 256, 0, stream>>>(k_w + i * 65536, ln1_w + i * 256, ln1_b + i * 256,
                                   nullptr, kvp + i * 131072, bias_kv + i * 512, 256);
    k_fold<<<64, 256, 0, stream>>>(v_w + i * 65536, ln1_w + i * 256, ln1_b + i * 256,
                                   nullptr, kvp + i * 131072 + 65536, bias_kv + i * 512 + 256, 256);
    k_fold<<<64, 256, 0, stream>>>(q_w + i * 65536, ln1_w + i * 256, ln1_b + i * 256,
                                   nullptr, qp + i * 65536, bias_q + i * 256, 256);
    k_fold<<<256, 256, 0, stream>>>(fc1_w + i * 262144, ln2_w + i * 256, ln2_b + i * 256,
                                    fc1_b + i * 1024, f1p + i * 262144, bias_f1 + i * 1024, 1024);
    k_cast4<<<64, 256, 0, stream>>>(proj_w + i * 65536, pjp + i * 65536, 16384);
    k_cast4<<<256, 256, 0, stream>>>(fc2_w + i * 262144, f2p + i * 262144, 65536);
  }
  // normalize patch tokens ONCE (identical across both CA blocks)
  k_norm<<<32400, 256, 0, stream>>>(x_patch, nxp, 129600);

  const float qscale = 0.25503489f;  // 1/sqrt(32) * log2(e)
  for (int i = 0; i < 2; i++) {
    k_norm<<<1200, 256, 0, stream>>>(xc, uncls, 4800);
    // patch K/V -> kvb planes (rowmap 1)
    k_gemm5<<<1013 * 4, 256, 0, stream>>>(nxp, kvp + i * 131072, 129600, 512, 256,
                                          0, 1, 2, 0.f, bias_kv + i * 512, nullptr,
                                          kvb, nullptr);
    // cls K/V -> kvb planes (rowmap 2)
    k_gemm5<<<38 * 4, 256, 0, stream>>>(uncls, kvp + i * 131072, 4800, 512, 256,
                                        0, 2, 2, 0.f, bias_kv + i * 512, nullptr,
                                        kvb, nullptr);
    k_gemm5<<<38 * 2, 256, 0, stream>>>(uncls, qp + i * 65536, 4800, 256, 256,
                                        1, 0, 1, qscale, bias_q + i * 256, nullptr,
                                        qb, nullptr);
    k_attn<<<1024, 256, 0, stream>>>(qb, kvb, pO, pml);
    k_acomb<<<512, 256, 0, stream>>>(pO, pml, ob);
    k_gemm5<<<38 * 2, 256, 0, stream>>>(ob, pjp + i * 65536, 4800, 256, 256,
                                        2, 0, 1, 0.f, proj_b + i * 256, gamma1 + i * 256,
                                        nullptr, xc);
    k_norm<<<1200, 256, 0, stream>>>(xc, xn, 4800);
    k_gemm5<<<38 * 8, 256, 0, stream>>>(xn, f1p + i * 262144, 4800, 1024, 256,
                                        3, 0, 3, 0.f, bias_f1 + i * 1024, nullptr,
                                        hb, nullptr);
    k_gemm5<<<38 * 2, 256, 0, stream>>>(hb, f2p + i * 262144, 4800, 256, 1024,
                                        2, 0, 1, 0.f, fc2_b + i * 256, gamma2 + i * 256,
                                        nullptr, xc);
  }
}

// Round 7
// 451.209 us; speedup vs baseline: 6.2177x; 1.5351x over previous
//
#include <hip/hip_runtime.h>
#include <cstdint>
#include <cstddef>

typedef unsigned short u16;
typedef float f32x4 __attribute__((ext_vector_type(4)));
typedef short s16x8 __attribute__((ext_vector_type(8)));
typedef unsigned short u16x4 __attribute__((ext_vector_type(4)));
typedef __bf16 bf16x8 __attribute__((ext_vector_type(8)));

#define DEV static __device__ __forceinline__

DEV u16 f2bf(float f) {
  uint32_t x = __float_as_uint(f);
  return (u16)((x + 0x7fffu + ((x >> 16) & 1u)) >> 16);  // RNE
}

DEV f32x4 mfma16(bf16x8 a, bf16x8 b, f32x4 c) {
  return __builtin_amdgcn_mfma_f32_16x16x32_bf16(a, b, c, 0, 0, 0);
}

DEV void mfma_bf16_asm(f32x4& acc, s16x8 a, s16x8 b) {
  asm volatile("v_mfma_f32_16x16x32_bf16 %0, %1, %2, %0" : "+v"(acc) : "v"(a), "v"(b));
}

DEV uint32_t pkbf(float lo, float hi) {
  uint32_t r;
  asm("v_cvt_pk_bf16_f32 %0, %1, %2" : "=v"(r) : "v"(lo), "v"(hi));
  return r;
}

DEV int swz(int b) { return b ^ ((b >> 2) & 0x70); }  // R2-proven byte swizzle

// ---------------- copy x_cls -> d_out ----------------
__global__ __launch_bounds__(256) void k_copy(const float* __restrict__ src,
                                              float* __restrict__ dst, int n4) {
  int i = blockIdx.x * blockDim.x + threadIdx.x;
  const float4* s = (const float4*)src;
  float4* d = (float4*)dst;
  for (; i < n4; i += gridDim.x * blockDim.x) d[i] = s[i];
}

// ---------------- fp32 -> bf16 cast (proj/fc2 weights) ----------------
__global__ __launch_bounds__(256) void k_cast4(const float* __restrict__ src,
                                               u16* __restrict__ dst, int n4) {
  int i = blockIdx.x * blockDim.x + threadIdx.x;
  for (; i < n4; i += gridDim.x * blockDim.x) {
    float4 v = ((const float4*)src)[i];
    u16x4 o;
    o[0] = f2bf(v.x); o[1] = f2bf(v.y); o[2] = f2bf(v.z); o[3] = f2bf(v.w);
    ((u16x4*)dst)[i] = o;
  }
}

// ---------------- Weight fold: Wout = W .* lw (bf16); bout = b0 + W @ lb ----------------
__global__ __launch_bounds__(256) void k_fold(const float* __restrict__ W,
                                              const float* __restrict__ lw,
                                              const float* __restrict__ lb,
                                              const float* __restrict__ b0,
                                              u16* __restrict__ Wout,
                                              float* __restrict__ bout, int nrows) {
  int wv = blockIdx.x * 4 + (threadIdx.x >> 6), lane = threadIdx.x & 63;
  if (wv >= nrows) return;
  float4 w4 = ((const float4*)(W + (size_t)wv * 256))[lane];
  float4 s4 = ((const float4*)lw)[lane];
  float4 t4 = ((const float4*)lb)[lane];
  u16x4 o;
  o[0] = f2bf(w4.x * s4.x); o[1] = f2bf(w4.y * s4.y);
  o[2] = f2bf(w4.z * s4.z); o[3] = f2bf(w4.w * s4.w);
  ((u16x4*)(Wout + (size_t)wv * 256))[lane] = o;
  float d = w4.x * t4.x + w4.y * t4.y + w4.z * t4.z + w4.w * t4.w;
#pragma unroll
  for (int m = 1; m < 64; m <<= 1) d += __shfl_xor(d, m, 64);
  if (lane == 0) bout[wv] = (b0 ? b0[wv] : 0.f) + d;
}

// ---------------- Pure normalize (affine folded into weights); compact out ----------
__global__ __launch_bounds__(256) void k_norm(const float* __restrict__ src,
                                              u16* __restrict__ out, int ntok) {
  int wv = blockIdx.x * 4 + (threadIdx.x >> 6), lane = threadIdx.x & 63;
  if (wv >= ntok) return;
  float4 v = ((const float4*)(src + (size_t)wv * 256))[lane];
  float s = v.x + v.y + v.z + v.w;
  float q = v.x * v.x + v.y * v.y + v.z * v.z + v.w * v.w;
#pragma unroll
  for (int m = 1; m < 64; m <<= 1) {
    s += __shfl_xor(s, m, 64);
    q += __shfl_xor(q, m, 64);
  }
  float mean = s * (1.f / 256.f);
  float var = q * (1.f / 256.f) - mean * mean;
  float rstd = rsqrtf(var + 1e-5f);
  u16x4 o;
  o[0] = f2bf((v.x - mean) * rstd);
  o[1] = f2bf((v.y - mean) * rstd);
  o[2] = f2bf((v.z - mean) * rstd);
  o[3] = f2bf((v.w - mean) * rstd);
  ((u16x4*)(out + (size_t)wv * 256))[lane] = o;
}

// ---------------- MFMA GEMM (R2-proven loop), small GEMMs only ----------------
// C[M,N] = A[M,K] @ Bw[N,K]^T + bias. 128x128 tile, 4 waves, BK=32.
// 1-D grid: by = bid & (2^lognby - 1).
// modes: 1 = obf[m*N+n] = bf16(v*scale)
//        2 = of32[m*N+n] += gamma[n]*v
//        3 = obf[m*N+n] = bf16(gelu(v))
__global__ __launch_bounds__(256) void k_gemm5(const u16* __restrict__ A,
                                               const u16* __restrict__ Bw,
                                               int M, int N, int K, int mode,
                                               int lognby, float scale,
                                               const float* __restrict__ bias,
                                               const float* __restrict__ gamma,
                                               u16* __restrict__ obf,
                                               float* __restrict__ of32) {
  __shared__ __align__(16) char smA[8192];
  __shared__ __align__(16) char smB[8192];
  const int tid = threadIdx.x;
  const int lane = tid & 63, wid = tid >> 6;
  const int wm = wid >> 1, wn = wid & 1;
  const int bid = blockIdx.x;
  const int by = bid & ((1 << lognby) - 1), bx = bid >> lognby;
  const int m0 = bx * 128, n0 = by * 128;
  const int g = lane >> 4, l15 = lane & 15;

  f32x4 acc[4][4] = {};

  for (int k0 = 0; k0 < K; k0 += 32) {
#pragma unroll
    for (int c = 0; c < 2; c++) {
      int e = tid + c * 256;
      int row = e >> 2, seg = e & 3;
      int am = m0 + row;
      if (am > M - 1) am = M - 1;
      s16x8 av = *(const s16x8*)(A + (size_t)am * K + k0 + seg * 8);
      *(s16x8*)(smA + swz(e * 16)) = av;
      s16x8 bv = *(const s16x8*)(Bw + (size_t)(n0 + row) * K + k0 + seg * 8);
      *(s16x8*)(smB + swz(e * 16)) = bv;
    }
    __syncthreads();
    s16x8 af[4], bfr[4];
#pragma unroll
    for (int i = 0; i < 4; i++) {
      int lm = wm * 64 + i * 16 + l15;
      af[i] = *(const s16x8*)(smA + swz(lm * 64 + g * 16));
      int ln = wn * 64 + i * 16 + l15;
      bfr[i] = *(const s16x8*)(smB + swz(ln * 64 + g * 16));
    }
#pragma unroll
    for (int i = 0; i < 4; i++)
#pragma unroll
      for (int j = 0; j < 4; j++) mfma_bf16_asm(acc[i][j], af[i], bfr[j]);
    __syncthreads();
  }
  asm volatile("s_nop 7\n\ts_nop 7" ::: "memory");  // MFMA -> VALU hazard guard

#pragma unroll
  for (int i = 0; i < 4; i++) {
#pragma unroll
    for (int j = 0; j < 4; j++) {
      int gmBase = m0 + wm * 64 + i * 16 + g * 4;
      int gn = n0 + wn * 64 + j * 16 + l15;
      float bs = bias[gn];
#pragma unroll
      for (int r = 0; r < 4; r++) {
        int gm = gmBase + r;
        if (gm >= M) continue;
        float v = acc[i][j][r] + bs;
        if (mode == 1) {
          obf[(size_t)gm * N + gn] = f2bf(v * scale);
        } else if (mode == 2) {
          of32[(size_t)gm * N + gn] += gamma[gn] * v;
        } else {
          obf[(size_t)gm * N + gn] = f2bf(0.5f * v * (1.f + erff(v * 0.70710678118654752f)));
        }
      }
    }
  }
}

// ---------------- Fused K/V-projection + flash attention ----------------
// Block = (b,h): b = bid&63, h = bid>>6. 4 waves; wave w owns token tiles w, w+4, ...
// Per tile: project K,V (nx @ Wkv^T + bias) via MFMA with head weights in LDS,
// redistribute through LDS (cvt_pk), then proven QK^T/softmax/PV.
// wkv: folded weights [512][256] bf16 (rows 0..255 K out-ch, 256..511 V out-ch).
// uncls: normalized cls [4800][256]; nxp: normalized patches [129600][256].
// qb: [4800][256] bf16 pre-scaled by 1/sqrt(32)*log2(e) (incl. folded bias).
__global__ __launch_bounds__(256, 2) void k_fattn(const u16* __restrict__ qb,
                                                  const u16* __restrict__ uncls,
                                                  const u16* __restrict__ nxp,
                                                  const u16* __restrict__ wkv,
                                                  const float* __restrict__ bias_kv,
                                                  u16* __restrict__ obf) {
  __shared__ __align__(16) char arena[55296];
  __shared__ float mlS[4][160];
  const int bid = blockIdx.x;
  const int b = bid & 63, h = bid >> 6;
  const int tid = threadIdx.x, lane = tid & 63, w = tid >> 6;
  const int l15 = lane & 15, g = lane >> 4;

  u16* WL = (u16*)arena;                                  // [64][256] u16, row-xor swizzle
  uint32_t* KL = (uint32_t*)(arena + 32768 + w * 2048);   // [32 tok][16 u32] (bf16 pairs)
  u16* VL = (u16*)(arena + 40960 + w * 2304);             // [32 tok][36 d] u16 (padded)
  uint32_t* PB = (uint32_t*)(arena + 50176 + w * 1280);   // [16 q][20 u32]

  // ---- stage head weights (Wk rows 0..31, Wv rows 32..63) ----
  for (int it = tid; it < 2048; it += 256) {
    int row = it >> 5, c16 = it & 31;
    int srcRow = (row < 32) ? (h * 32 + row) : (256 + h * 32 + (row - 32));
    s16x8 w8 = *(const s16x8*)(wkv + (size_t)srcRow * 256 + c16 * 8);
    *(s16x8*)(WL + row * 256 + (((c16 * 16) ^ ((row & 7) << 4)) >> 1)) = w8;
  }

  // ---- per-lane bias regs: d = s*16 + 4g + r ----
  float bk[2][4], bvb[2][4];
#pragma unroll
  for (int s2 = 0; s2 < 2; s2++)
#pragma unroll
    for (int r = 0; r < 4; r++) {
      bk[s2][r] = bias_kv[h * 32 + s2 * 16 + 4 * g + r];
      bvb[s2][r] = bias_kv[256 + h * 32 + s2 * 16 + 4 * g + r];
    }

  // ---- Q fragments (resident) ----
  bf16x8 bq[5];
#pragma unroll
  for (int qt = 0; qt < 5; qt++) {
    int q = qt * 16 + l15; if (q > 74) q = 74;
    s16x8 qv = *(const s16x8*)(qb + (size_t)(b * 75 + q) * 256 + h * 32 + g * 8);
    bq[qt] = __builtin_bit_cast(bf16x8, qv);
  }

  f32x4 acc[5][2] = {};
  float mlc[5], llc[5];
#pragma unroll
  for (int qt = 0; qt < 5; qt++) { mlc[qt] = -1e30f; llc[qt] = 0.f; }

  __syncthreads();  // weights staged

  const int xw = (l15 & 7) << 4;   // weight-row xor (same for rows l15,16+l15,32+l15,48+l15)
  const int xk = (l15 & 3) << 2;   // Klds slot xor

  for (int tt = w; tt < 66; tt += 4) {
    const int t0 = tt * 32;
    int tA = t0 + l15;      if (tA > 2099) tA = 2099;
    int tB = t0 + 16 + l15; if (tB > 2099) tB = 2099;
    const u16* rowA = (tA < 75) ? uncls + ((size_t)b * 75 + tA) * 256
                                : nxp + ((size_t)b * 2025 + (tA - 75)) * 256;
    const u16* rowB = (tB < 75) ? uncls + ((size_t)b * 75 + tB) * 256
                                : nxp + ((size_t)b * 2025 + (tB - 75)) * 256;

    // ---- project K,V: C[d][token], 8 ksteps over 256 ch ----
    f32x4 aK[2][2] = {}, aV[2][2] = {};
    __builtin_amdgcn_s_setprio(1);
#pragma unroll
    for (int ks = 0; ks < 8; ks++) {
      bf16x8 nA = __builtin_bit_cast(bf16x8, *(const s16x8*)(rowA + ks * 32 + g * 8));
      bf16x8 nB = __builtin_bit_cast(bf16x8, *(const s16x8*)(rowB + ks * 32 + g * 8));
      const int cb = (ks * 64 + g * 16) ^ xw;
      bf16x8 k0 = __builtin_bit_cast(bf16x8, *(const s16x8*)(WL + l15 * 256 + (cb >> 1)));
      bf16x8 k1 = __builtin_bit_cast(bf16x8, *(const s16x8*)(WL + (16 + l15) * 256 + (cb >> 1)));
      bf16x8 w0 = __builtin_bit_cast(bf16x8, *(const s16x8*)(WL + (32 + l15) * 256 + (cb >> 1)));
      bf16x8 w1 = __builtin_bit_cast(bf16x8, *(const s16x8*)(WL + (48 + l15) * 256 + (cb >> 1)));
      aK[0][0] = mfma16(k0, nA, aK[0][0]);
      aK[0][1] = mfma16(k0, nB, aK[0][1]);
      aK[1][0] = mfma16(k1, nA, aK[1][0]);
      aK[1][1] = mfma16(k1, nB, aK[1][1]);
      aV[0][0] = mfma16(w0, nA, aV[0][0]);
      aV[0][1] = mfma16(w0, nB, aV[0][1]);
      aV[1][0] = mfma16(w1, nA, aV[1][0]);
      aV[1][1] = mfma16(w1, nB, aV[1][1]);
    }
    __builtin_amdgcn_s_setprio(0);

    // ---- pack K/V (+bias) into per-wave LDS tiles ----
#pragma unroll
    for (int s2 = 0; s2 < 2; s2++)
#pragma unroll
      for (int u = 0; u < 2; u++) {
        const int trow = u * 16 + l15;
        f32x4 kk4 = aK[s2][u];
        uint2 pk2;
        pk2.x = pkbf(kk4[0] + bk[s2][0], kk4[1] + bk[s2][1]);
        pk2.y = pkbf(kk4[2] + bk[s2][2], kk4[3] + bk[s2][3]);
        *(uint2*)&KL[trow * 16 + ((s2 * 8 + 2 * g) ^ ((trow & 3) << 2))] = pk2;
        f32x4 vv4 = aV[s2][u];
        uint32_t pv0 = pkbf(vv4[0] + bvb[s2][0], vv4[1] + bvb[s2][1]);
        uint32_t pv1 = pkbf(vv4[2] + bvb[s2][2], vv4[3] + bvb[s2][3]);
        *(uint32_t*)&VL[trow * 36 + s2 * 16 + 4 * g] = pv0;
        *(uint32_t*)&VL[trow * 36 + s2 * 16 + 4 * g + 2] = pv1;
      }

    // ---- K fragments (row=token=l15 / 16+l15, k=d=8g..8g+7) ----
    uint4 ka = *(const uint4*)&KL[l15 * 16 + ((4 * g) ^ xk)];
    uint4 kb = *(const uint4*)&KL[(16 + l15) * 16 + ((4 * g) ^ xk)];
    bf16x8 bA = __builtin_bit_cast(bf16x8, ka);
    bf16x8 bB = __builtin_bit_cast(bf16x8, kb);
    // ---- V fragments (col=d=l15/16+l15, k=token=8g..8g+7) ----
    s16x8 v0, v1;
#pragma unroll
    for (int e = 0; e < 8; e++) {
      v0[e] = (short)VL[(8 * g + e) * 36 + l15];
      v1[e] = (short)VL[(8 * g + e) * 36 + 16 + l15];
    }
    bf16x8 bv0 = __builtin_bit_cast(bf16x8, v0);
    bf16x8 bv1 = __builtin_bit_cast(bf16x8, v1);

    const bool lastTile = (t0 == 2080);

#pragma unroll
    for (int qt = 0; qt < 5; qt++) {
      f32x4 z = {0.f, 0.f, 0.f, 0.f};
      f32x4 sA = mfma16(bA, bq[qt], z);
      f32x4 sB = mfma16(bB, bq[qt], z);
      if (lastTile && g >= 1) {   // tokens t0+16+4g+r >= 2100
        sB[0] = sB[1] = sB[2] = sB[3] = -1e30f;
      }
      float px = fmaxf(fmaxf(fmaxf(sA[0], sA[1]), fmaxf(sA[2], sA[3])),
                       fmaxf(fmaxf(sB[0], sB[1]), fmaxf(sB[2], sB[3])));
      px = fmaxf(px, __shfl_xor(px, 16, 64));
      px = fmaxf(px, __shfl_xor(px, 32, 64));
      float mq = mlc[qt];
      if (!__all(px <= mq + 8.f)) {   // defer-max (T13)
        float mn = fmaxf(mq, px);
        float rs = exp2f(mq - mn);
        mlc[qt] = mn;
        llc[qt] *= rs;
#pragma unroll
        for (int r = 0; r < 4; r++) {
          float rr = __shfl(rs, ((lane >> 4) << 2) + r, 64);
          acc[qt][0][r] *= rr;
          acc[qt][1][r] *= rr;
        }
        mq = mn;
      }
      f32x4 pA, pB;
#pragma unroll
      for (int r = 0; r < 4; r++) {
        pA[r] = exp2f(sA[r] - mq);
        pB[r] = exp2f(sB[r] - mq);
      }
      float ps = pA[0] + pA[1] + pA[2] + pA[3] + pB[0] + pB[1] + pB[2] + pB[3];
      ps += __shfl_xor(ps, 16, 64);
      ps += __shfl_xor(ps, 32, 64);
      llc[qt] += ps;
      uint32_t* Pu = &PB[l15 * 20];
      Pu[2 * g]     = pkbf(pA[0], pA[1]);
      Pu[2 * g + 1] = pkbf(pA[2], pA[3]);
      Pu[8 + 2 * g]     = pkbf(pB[0], pB[1]);
      Pu[8 + 2 * g + 1] = pkbf(pB[2], pB[3]);
      uint4 pu = *(const uint4*)&PB[l15 * 20 + 4 * g];
      bf16x8 bp = __builtin_bit_cast(bf16x8, pu);
      acc[qt][0] = mfma16(bp, bv0, acc[qt][0]);
      acc[qt][1] = mfma16(bp, bv1, acc[qt][1]);
    }
  }

  // ---- combine 4 wave-partials (reuse arena for O partials) ----
  __syncthreads();   // everyone done with WL/KL/VL
  float* MC = (float*)arena;   // [4][2560]
#pragma unroll
  for (int qt = 0; qt < 5; qt++)
#pragma unroll
    for (int dh = 0; dh < 2; dh++)
#pragma unroll
      for (int r = 0; r < 4; r++) {
        int q = qt * 16 + 4 * g + r;
        MC[w * 2560 + q * 32 + dh * 16 + l15] = acc[qt][dh][r];
      }
  if (lane < 16) {
#pragma unroll
    for (int qt = 0; qt < 5; qt++) {
      mlS[w][qt * 16 + l15] = mlc[qt];
      mlS[w][80 + qt * 16 + l15] = llc[qt];
    }
  }
  __syncthreads();

  for (int idx = tid; idx < 2400; idx += 256) {
    int q = idx >> 5, d = idx & 31;
    float M = -1e30f;
#pragma unroll
    for (int ww = 0; ww < 4; ww++) M = fmaxf(M, mlS[ww][q]);
    float L = 0.f, O = 0.f;
#pragma unroll
    for (int ww = 0; ww < 4; ww++) {
      float sc = exp2f(mlS[ww][q] - M);
      L += mlS[ww][80 + q] * sc;
      O += MC[ww * 2560 + q * 32 + d] * sc;
    }
    obf[(size_t)(b * 75 + q) * 256 + h * 32 + d] = f2bf(O / L);
  }
}

// ---------------- host ----------------
extern "C" void kernel_launch(void* const* d_in, const int* in_sizes, int n_in,
                              void* d_out, int out_size, void* d_ws, size_t ws_size,
                              hipStream_t stream) {
  const float* x_cls   = (const float*)d_in[0];
  const float* x_patch = (const float*)d_in[1];
  const float* ln1_w   = (const float*)d_in[2];
  const float* ln1_b   = (const float*)d_in[3];
  const float* q_w     = (const float*)d_in[4];
  const float* k_w     = (const float*)d_in[5];
  const float* v_w     = (const float*)d_in[6];
  const float* proj_w  = (const float*)d_in[7];
  const float* proj_b  = (const float*)d_in[8];
  const float* ln2_w   = (const float*)d_in[9];
  const float* ln2_b   = (const float*)d_in[10];
  const float* fc1_w   = (const float*)d_in[11];
  const float* fc1_b   = (const float*)d_in[12];
  const float* fc2_w   = (const float*)d_in[13];
  const float* fc2_b   = (const float*)d_in[14];
  const float* gamma1  = (const float*)d_in[15];
  const float* gamma2  = (const float*)d_in[16];
  float* xc = (float*)d_out;

  char* ws = (char*)d_ws;
  size_t off = 0;
  auto alloc = [&](size_t bytes) {
    char* p = ws + off;
    off += (bytes + 255) & ~(size_t)255;
    return p;
  };
  u16* nxp   = (u16*)alloc(129600ull * 256 * 2);  // normalized patches (shared by both layers)
  u16* uncls = (u16*)alloc(4800ull * 256 * 2);    // normalized cls tokens
  u16* qb    = (u16*)alloc(4800ull * 256 * 2);
  u16* ob    = (u16*)alloc(4800ull * 256 * 2);
  u16* xn    = (u16*)alloc(4800ull * 256 * 2);
  u16* hb    = (u16*)alloc(4800ull * 1024 * 2);
  u16* qp    = (u16*)alloc(2ull * 65536 * 2);
  u16* kvp   = (u16*)alloc(2ull * 131072 * 2);
  u16* pjp   = (u16*)alloc(2ull * 65536 * 2);
  u16* f1p   = (u16*)alloc(2ull * 262144 * 2);
  u16* f2p   = (u16*)alloc(2ull * 262144 * 2);
  float* bias_kv = (float*)alloc(2ull * 512 * 4);
  float* bias_q  = (float*)alloc(2ull * 256 * 4);
  float* bias_f1 = (float*)alloc(2ull * 1024 * 4);

  k_copy<<<1200, 256, 0, stream>>>(x_cls, xc, 307200);
  for (int i = 0; i < 2; i++) {
    k_fold<<<64, 256, 0, stream>>>(k_w + i * 65536, ln1_w + i * 256, ln1_b + i * 256,
                                   nullptr, kvp + i * 131072, bias_kv + i * 512, 256);
    k_fold<<<64, 256, 0, stream>>>(v_w + i * 65536, ln1_w + i * 256, ln1_b + i * 256,
                                   nullptr, kvp + i * 131072 + 65536, bias_kv + i * 512 + 256, 256);
    k_fold<<<64, 256, 0, stream>>>(q_w + i * 65536, ln1_w + i * 256, ln1_b + i * 256,
                                   nullptr, qp + i * 65536, bias_q + i * 256, 256);
    k_fold<<<256, 256, 0, stream>>>(fc1_w + i * 262144, ln2_w + i * 256, ln2_b + i * 256,
                                    fc1_b + i * 1024, f1p + i * 262144, bias_f1 + i * 1024, 1024);
    k_cast4<<<64, 256, 0, stream>>>(proj_w + i * 65536, pjp + i * 65536, 16384);
    k_cast4<<<256, 256, 0, stream>>>(fc2_w + i * 262144, f2p + i * 262144, 65536);
  }
  // normalize patch tokens ONCE (identical across both CA blocks)
  k_norm<<<32400, 256, 0, stream>>>(x_patch, nxp, 129600);

  const float qscale = 0.25503489f;  // 1/sqrt(32) * log2(e)
  for (int i = 0; i < 2; i++) {
    k_norm<<<1200, 256, 0, stream>>>(xc, uncls, 4800);
    k_gemm5<<<38 * 2, 256, 0, stream>>>(uncls, qp + i * 65536, 4800, 256, 256,
                                        1, 1, qscale, bias_q + i * 256, nullptr,
                                        qb, nullptr);
    k_fattn<<<512, 256, 0, stream>>>(qb, uncls, nxp, kvp + i * 131072,
                                     bias_kv + i * 512, ob);
    k_gemm5<<<38 * 2, 256, 0, stream>>>(ob, pjp + i * 65536, 4800, 256, 256,
                                        2, 1, 0.f, proj_b + i * 256, gamma1 + i * 256,
                                        nullptr, xc);
    k_norm<<<1200, 256, 0, stream>>>(xc, xn, 4800);
    k_gemm5<<<38 * 8, 256, 0, stream>>>(xn, f1p + i * 262144, 4800, 1024, 256,
                                        3, 3, 0.f, bias_f1 + i * 1024, nullptr,
                                        hb, nullptr);
    k_gemm5<<<38 * 2, 256, 0, stream>>>(hb, f2p + i * 262144, 4800, 256, 1024,
                                        2, 1, 0.f, fc2_b + i * 256, gamma2 + i * 256,
                                        nullptr, xc);
  }
}

// Round 8
// 364.933 us; speedup vs baseline: 7.6877x; 1.2364x over previous
//
#include <hip/hip_runtime.h>
#include <cstdint>
#include <cstddef>

typedef unsigned short u16;
typedef float f32x4 __attribute__((ext_vector_type(4)));
typedef short s16x8 __attribute__((ext_vector_type(8)));
typedef unsigned short u16x4 __attribute__((ext_vector_type(4)));
typedef __bf16 bf16x8 __attribute__((ext_vector_type(8)));

#define DEV static __device__ __forceinline__

DEV u16 f2bf(float f) {
  uint32_t x = __float_as_uint(f);
  return (u16)((x + 0x7fffu + ((x >> 16) & 1u)) >> 16);  // RNE
}

DEV f32x4 mfma16(bf16x8 a, bf16x8 b, f32x4 c) {
  return __builtin_amdgcn_mfma_f32_16x16x32_bf16(a, b, c, 0, 0, 0);
}

DEV void mfma_bf16_asm(f32x4& acc, s16x8 a, s16x8 b) {
  asm volatile("v_mfma_f32_16x16x32_bf16 %0, %1, %2, %0" : "+v"(acc) : "v"(a), "v"(b));
}

DEV uint32_t pkbf(float lo, float hi) {
  uint32_t r;
  asm("v_cvt_pk_bf16_f32 %0, %1, %2" : "=v"(r) : "v"(lo), "v"(hi));
  return r;
}

// ---------------- mega prep: folds + casts + x_cls copy + patch norm ----------------
// jb ranges: [0,1536) weight jobs (768/layer); [1536,2736) x_cls copy; [2736,35136) patch norm
__global__ __launch_bounds__(256) void k_prep(
    const float* __restrict__ x_cls, const float* __restrict__ x_patch,
    const float* __restrict__ k_w, const float* __restrict__ v_w,
    const float* __restrict__ q_w, const float* __restrict__ proj_w,
    const float* __restrict__ fc1_w, const float* __restrict__ fc2_w,
    const float* __restrict__ ln1_w, const float* __restrict__ ln1_b,
    const float* __restrict__ ln2_w, const float* __restrict__ ln2_b,
    const float* __restrict__ fc1_b,
    u16* __restrict__ kvp, u16* __restrict__ qp, u16* __restrict__ pjp,
    u16* __restrict__ f1p, u16* __restrict__ f2p,
    float* __restrict__ bias_kv, float* __restrict__ bias_q, float* __restrict__ bias_f1,
    float* __restrict__ xc, u16* __restrict__ nxp) {
  const int jb = blockIdx.x;
  const int lane = threadIdx.x & 63;
  if (jb >= 2736) {
    // patch normalize: 4 tokens per block
    int wv = (jb - 2736) * 4 + (threadIdx.x >> 6);
    if (wv >= 129600) return;
    float4 v = ((const float4*)(x_patch + (size_t)wv * 256))[lane];
    float s = v.x + v.y + v.z + v.w;
    float q = v.x * v.x + v.y * v.y + v.z * v.z + v.w * v.w;
#pragma unroll
    for (int m = 1; m < 64; m <<= 1) {
      s += __shfl_xor(s, m, 64);
      q += __shfl_xor(q, m, 64);
    }
    float mean = s * (1.f / 256.f);
    float var = q * (1.f / 256.f) - mean * mean;
    float rstd = rsqrtf(var + 1e-5f);
    u16x4 o;
    o[0] = f2bf((v.x - mean) * rstd);
    o[1] = f2bf((v.y - mean) * rstd);
    o[2] = f2bf((v.z - mean) * rstd);
    o[3] = f2bf((v.w - mean) * rstd);
    ((u16x4*)(nxp + (size_t)wv * 256))[lane] = o;
    return;
  }
  if (jb >= 1536) {
    int i = (jb - 1536) * 256 + threadIdx.x;   // 307200 float4s over 1200 blocks
    ((float4*)xc)[i] = ((const float4*)x_cls)[i];
    return;
  }
  const int layer = jb >= 768 ? 1 : 0;
  const int j = jb - layer * 768;
  const float* W;
  const float* lw = ln1_w + layer * 256;
  const float* lb = ln1_b + layer * 256;
  const float* b0 = nullptr;
  u16* Wout;
  float* bout = nullptr;
  int rowoff;
  if (j < 64)       { W = k_w + layer * 65536;    Wout = kvp + layer * 131072;         bout = bias_kv + layer * 512;       rowoff = j * 4; }
  else if (j < 128) { W = v_w + layer * 65536;    Wout = kvp + layer * 131072 + 65536; bout = bias_kv + layer * 512 + 256; rowoff = (j - 64) * 4; }
  else if (j < 192) { W = q_w + layer * 65536;    Wout = qp + layer * 65536;           bout = bias_q + layer * 256;        rowoff = (j - 128) * 4; }
  else if (j < 448) { W = fc1_w + layer * 262144; lw = ln2_w + layer * 256; lb = ln2_b + layer * 256; b0 = fc1_b + layer * 1024;
                      Wout = f1p + layer * 262144; bout = bias_f1 + layer * 1024;      rowoff = (j - 192) * 4; }
  else if (j < 512) { W = proj_w + layer * 65536; lw = nullptr;                        Wout = pjp + layer * 65536;         rowoff = (j - 448) * 4; }
  else              { W = fc2_w + layer * 262144; lw = nullptr;                        Wout = f2p + layer * 262144;        rowoff = (j - 512) * 4; }
  const int wv = rowoff + (threadIdx.x >> 6);
  float4 w4 = ((const float4*)(W + (size_t)wv * 256))[lane];
  u16x4 o;
  if (lw) {
    float4 s4 = ((const float4*)lw)[lane];
    o[0] = f2bf(w4.x * s4.x); o[1] = f2bf(w4.y * s4.y);
    o[2] = f2bf(w4.z * s4.z); o[3] = f2bf(w4.w * s4.w);
  } else {
    o[0] = f2bf(w4.x); o[1] = f2bf(w4.y); o[2] = f2bf(w4.z); o[3] = f2bf(w4.w);
  }
  ((u16x4*)(Wout + (size_t)wv * 256))[lane] = o;
  if (bout) {
    float4 t4 = ((const float4*)lb)[lane];
    float d = w4.x * t4.x + w4.y * t4.y + w4.z * t4.z + w4.w * t4.w;
#pragma unroll
    for (int m = 1; m < 64; m <<= 1) d += __shfl_xor(d, m, 64);
    if (lane == 0) bout[wv] = (b0 ? b0[wv] : 0.f) + d;
  }
}

// ---------------- Pure normalize (affine folded into weights); compact out ----------
__global__ __launch_bounds__(256) void k_norm(const float* __restrict__ src,
                                              u16* __restrict__ out, int ntok) {
  int wv = blockIdx.x * 4 + (threadIdx.x >> 6), lane = threadIdx.x & 63;
  if (wv >= ntok) return;
  float4 v = ((const float4*)(src + (size_t)wv * 256))[lane];
  float s = v.x + v.y + v.z + v.w;
  float q = v.x * v.x + v.y * v.y + v.z * v.z + v.w * v.w;
#pragma unroll
  for (int m = 1; m < 64; m <<= 1) {
    s += __shfl_xor(s, m, 64);
    q += __shfl_xor(q, m, 64);
  }
  float mean = s * (1.f / 256.f);
  float var = q * (1.f / 256.f) - mean * mean;
  float rstd = rsqrtf(var + 1e-5f);
  u16x4 o;
  o[0] = f2bf((v.x - mean) * rstd);
  o[1] = f2bf((v.y - mean) * rstd);
  o[2] = f2bf((v.z - mean) * rstd);
  o[3] = f2bf((v.w - mean) * rstd);
  ((u16x4*)(out + (size_t)wv * 256))[lane] = o;
}

// ---------------- small-M MFMA GEMM: 64x128 tile, BK=64, M=4800 exact ----------------
// C[M,N] = A[M,K] @ Bw[N,K]^T + bias. 4 waves (2x2), wave-tile 32x64.
// 1-D grid: by = bid & (2^lognby - 1), bx = bid >> lognby.
// modes: 1 = obf[m*N+n] = bf16(v*scale); 2 = of32[m*N+n] += gamma[n]*v;
//        3 = obf[m*N+n] = bf16(gelu(v))
__global__ __launch_bounds__(256) void k_gemm6(const u16* __restrict__ A,
                                               const u16* __restrict__ Bw,
                                               int N, int K, int mode,
                                               int lognby, float scale,
                                               const float* __restrict__ bias,
                                               const float* __restrict__ gamma,
                                               u16* __restrict__ obf,
                                               float* __restrict__ of32) {
  __shared__ __align__(16) char smA[8192];    // [64][64] u16, xor-swizzled 16B slots
  __shared__ __align__(16) char smB[16384];   // [128][64]
  const int tid = threadIdx.x, lane = tid & 63, wid = tid >> 6;
  const int wm = wid >> 1, wn = wid & 1;
  const int bid = blockIdx.x;
  const int by = bid & ((1 << lognby) - 1), bx = bid >> lognby;
  const int m0 = bx * 64, n0 = by * 128;
  const int g = lane >> 4, l15 = lane & 15;

  f32x4 acc[2][4] = {};

  for (int k0 = 0; k0 < K; k0 += 64) {
#pragma unroll
    for (int c = 0; c < 2; c++) {
      int ee = tid + 256 * c;
      int row = ee >> 3, sl = ee & 7;
      s16x8 av = *(const s16x8*)(A + (size_t)(m0 + row) * K + k0 + sl * 8);
      *(s16x8*)(smA + row * 128 + ((sl * 16) ^ ((row & 7) << 4))) = av;
    }
#pragma unroll
    for (int c = 0; c < 4; c++) {
      int ee = tid + 256 * c;
      int row = ee >> 3, sl = ee & 7;
      s16x8 bv = *(const s16x8*)(Bw + (size_t)(n0 + row) * K + k0 + sl * 8);
      *(s16x8*)(smB + row * 128 + ((sl * 16) ^ ((row & 7) << 4))) = bv;
    }
    __syncthreads();
    s16x8 af[2][2], bfr[4][2];
#pragma unroll
    for (int s = 0; s < 2; s++) {
#pragma unroll
      for (int i = 0; i < 2; i++) {
        int r = wm * 32 + i * 16 + l15;
        af[i][s] = *(const s16x8*)(smA + r * 128 + (((s * 4 + g) * 16) ^ ((r & 7) << 4)));
      }
#pragma unroll
      for (int jj = 0; jj < 4; jj++) {
        int n = wn * 64 + jj * 16 + l15;
        bfr[jj][s] = *(const s16x8*)(smB + n * 128 + (((s * 4 + g) * 16) ^ ((n & 7) << 4)));
      }
    }
#pragma unroll
    for (int s = 0; s < 2; s++)
#pragma unroll
      for (int i = 0; i < 2; i++)
#pragma unroll
        for (int jj = 0; jj < 4; jj++)
          mfma_bf16_asm(acc[i][jj], af[i][s], bfr[jj][s]);
    __syncthreads();
  }
  asm volatile("s_nop 7\n\ts_nop 7" ::: "memory");

#pragma unroll
  for (int i = 0; i < 2; i++) {
#pragma unroll
    for (int jj = 0; jj < 4; jj++) {
      int gmBase = m0 + wm * 32 + i * 16 + g * 4;
      int gn = n0 + wn * 64 + jj * 16 + l15;
      float bs = bias[gn];
#pragma unroll
      for (int r = 0; r < 4; r++) {
        int gm = gmBase + r;
        float v = acc[i][jj][r] + bs;
        if (mode == 1) {
          obf[(size_t)gm * N + gn] = f2bf(v * scale);
        } else if (mode == 2) {
          of32[(size_t)gm * N + gn] += gamma[gn] * v;
        } else {
          obf[(size_t)gm * N + gn] = f2bf(0.5f * v * (1.f + erff(v * 0.70710678118654752f)));
        }
      }
    }
  }
}

// ---------------- Fused K/V-projection + flash attention ----------------
// Block = (b,h). 4 waves; wave w owns token tiles w, w+4, ...
// LDS: WL 32KB + per-wave {KL(2048B, overlaid by PB 1280B) + VL 2304B} -> 52.7KB, 3 blk/CU.
__global__ __launch_bounds__(256, 3) void k_fattn(const u16* __restrict__ qb,
                                                  const u16* __restrict__ uncls,
                                                  const u16* __restrict__ nxp,
                                                  const u16* __restrict__ wkv,
                                                  const float* __restrict__ bias_kv,
                                                  u16* __restrict__ obf) {
  __shared__ __align__(16) char arena[50176];
  __shared__ float mlS[4][160];
  const int bid = blockIdx.x;
  const int b = bid & 63, h = bid >> 6;
  const int tid = threadIdx.x, lane = tid & 63, w = tid >> 6;
  const int l15 = lane & 15, g = lane >> 4;

  u16* WL = (u16*)arena;                      // [64][256] u16, row-xor swizzle
  char* wb = arena + 32768 + w * 4352;
  uint32_t* KL = (uint32_t*)wb;               // [32 tok][16 u32], xor ((trow>>2)&3)<<2
  uint32_t* PB = (uint32_t*)wb;               // overlay: [16 q][20 u32]
  u16* VL = (u16*)(wb + 2048);                // [32 tok][36 d] u16, d-slot xor (trow&16)

  // ---- stage head weights (Wk rows 0..31, Wv rows 32..63) ----
  for (int it = tid; it < 2048; it += 256) {
    int row = it >> 5, c16 = it & 31;
    int srcRow = (row < 32) ? (h * 32 + row) : (256 + h * 32 + (row - 32));
    s16x8 w8 = *(const s16x8*)(wkv + (size_t)srcRow * 256 + c16 * 8);
    *(s16x8*)(WL + row * 256 + (((c16 * 16) ^ ((row & 7) << 4)) >> 1)) = w8;
  }

  float bk[2][4], bvb[2][4];
#pragma unroll
  for (int s2 = 0; s2 < 2; s2++)
#pragma unroll
    for (int r = 0; r < 4; r++) {
      bk[s2][r] = bias_kv[h * 32 + s2 * 16 + 4 * g + r];
      bvb[s2][r] = bias_kv[256 + h * 32 + s2 * 16 + 4 * g + r];
    }

  bf16x8 bq[5];
#pragma unroll
  for (int qt = 0; qt < 5; qt++) {
    int q = qt * 16 + l15; if (q > 74) q = 74;
    s16x8 qv = *(const s16x8*)(qb + (size_t)(b * 75 + q) * 256 + h * 32 + g * 8);
    bq[qt] = __builtin_bit_cast(bf16x8, qv);
  }

  f32x4 acc[5][2] = {};
  float mlc[5], llc[5];
#pragma unroll
  for (int qt = 0; qt < 5; qt++) { mlc[qt] = -1e30f; llc[qt] = 0.f; }

  __syncthreads();  // weights staged

  const int xw = (l15 & 7) << 4;             // weight-row xor
  const int xK = ((l15 >> 2) & 3) << 2;      // KL slot xor (per token row l15 / 16+l15)

  for (int tt = w; tt < 66; tt += 4) {
    const int t0 = tt * 32;
    int tA = t0 + l15;      if (tA > 2099) tA = 2099;
    int tB = t0 + 16 + l15; if (tB > 2099) tB = 2099;
    const u16* rowA = (tA < 75) ? uncls + ((size_t)b * 75 + tA) * 256
                                : nxp + ((size_t)b * 2025 + (tA - 75)) * 256;
    const u16* rowB = (tB < 75) ? uncls + ((size_t)b * 75 + tB) * 256
                                : nxp + ((size_t)b * 2025 + (tB - 75)) * 256;

    // ---- project K,V: C[d][token], 8 ksteps over 256 ch ----
    f32x4 aK[2][2] = {}, aV[2][2] = {};
    __builtin_amdgcn_s_setprio(1);
#pragma unroll
    for (int ks = 0; ks < 8; ks++) {
      bf16x8 nA = __builtin_bit_cast(bf16x8, *(const s16x8*)(rowA + ks * 32 + g * 8));
      bf16x8 nB = __builtin_bit_cast(bf16x8, *(const s16x8*)(rowB + ks * 32 + g * 8));
      const int cb = (ks * 64 + g * 16) ^ xw;
      bf16x8 k0 = __builtin_bit_cast(bf16x8, *(const s16x8*)(WL + l15 * 256 + (cb >> 1)));
      bf16x8 k1 = __builtin_bit_cast(bf16x8, *(const s16x8*)(WL + (16 + l15) * 256 + (cb >> 1)));
      bf16x8 w0 = __builtin_bit_cast(bf16x8, *(const s16x8*)(WL + (32 + l15) * 256 + (cb >> 1)));
      bf16x8 w1 = __builtin_bit_cast(bf16x8, *(const s16x8*)(WL + (48 + l15) * 256 + (cb >> 1)));
      aK[0][0] = mfma16(k0, nA, aK[0][0]);
      aK[0][1] = mfma16(k0, nB, aK[0][1]);
      aK[1][0] = mfma16(k1, nA, aK[1][0]);
      aK[1][1] = mfma16(k1, nB, aK[1][1]);
      aV[0][0] = mfma16(w0, nA, aV[0][0]);
      aV[0][1] = mfma16(w0, nB, aV[0][1]);
      aV[1][0] = mfma16(w1, nA, aV[1][0]);
      aV[1][1] = mfma16(w1, nB, aV[1][1]);
    }
    __builtin_amdgcn_s_setprio(0);

    // ---- pack K/V (+bias) into per-wave LDS tiles (b64 writes, verified swizzles) ----
#pragma unroll
    for (int s2 = 0; s2 < 2; s2++)
#pragma unroll
      for (int u = 0; u < 2; u++) {
        const int trow = u * 16 + l15;
        f32x4 kk4 = aK[s2][u];
        uint2 pk2;
        pk2.x = pkbf(kk4[0] + bk[s2][0], kk4[1] + bk[s2][1]);
        pk2.y = pkbf(kk4[2] + bk[s2][2], kk4[3] + bk[s2][3]);
        *(uint2*)&KL[trow * 16 + ((s2 * 8 + 2 * g) ^ xK)] = pk2;
        f32x4 vv4 = aV[s2][u];
        uint2 pv2;
        pv2.x = pkbf(vv4[0] + bvb[s2][0], vv4[1] + bvb[s2][1]);
        pv2.y = pkbf(vv4[2] + bvb[s2][2], vv4[3] + bvb[s2][3]);
        *(uint2*)&VL[trow * 36 + ((s2 * 16 + 4 * g) ^ (u << 4))] = pv2;
      }

    // ---- K fragments ----
    uint4 ka = *(const uint4*)&KL[l15 * 16 + ((4 * g) ^ xK)];
    uint4 kb = *(const uint4*)&KL[(16 + l15) * 16 + ((4 * g) ^ xK)];
    bf16x8 bA = __builtin_bit_cast(bf16x8, ka);
    bf16x8 bB = __builtin_bit_cast(bf16x8, kb);
    // ---- V fragments (conflict-free scalar reads via token-bit-4 xor) ----
    s16x8 v0, v1;
#pragma unroll
    for (int e = 0; e < 8; e++) {
      int vrow = 8 * g + e;
      int mx = vrow & 16;
      v0[e] = (short)VL[vrow * 36 + (l15 ^ mx)];
      v1[e] = (short)VL[vrow * 36 + ((16 + l15) ^ mx)];
    }
    bf16x8 bv0 = __builtin_bit_cast(bf16x8, v0);
    bf16x8 bv1 = __builtin_bit_cast(bf16x8, v1);

    const bool lastTile = (t0 == 2080);

#pragma unroll
    for (int qt = 0; qt < 5; qt++) {
      f32x4 z = {0.f, 0.f, 0.f, 0.f};
      f32x4 sA = mfma16(bA, bq[qt], z);
      f32x4 sB = mfma16(bB, bq[qt], z);
      if (lastTile && g >= 1) {   // tokens t0+16+4g+r >= 2100
        sB[0] = sB[1] = sB[2] = sB[3] = -1e30f;
      }
      float px = fmaxf(fmaxf(fmaxf(sA[0], sA[1]), fmaxf(sA[2], sA[3])),
                       fmaxf(fmaxf(sB[0], sB[1]), fmaxf(sB[2], sB[3])));
      px = fmaxf(px, __shfl_xor(px, 16, 64));
      px = fmaxf(px, __shfl_xor(px, 32, 64));
      float mq = mlc[qt];
      if (!__all(px <= mq + 8.f)) {   // defer-max (T13)
        float mn = fmaxf(mq, px);
        float rs = exp2f(mq - mn);
        mlc[qt] = mn;
        llc[qt] *= rs;
#pragma unroll
        for (int r = 0; r < 4; r++) {
          float rr = __shfl(rs, ((lane >> 4) << 2) + r, 64);
          acc[qt][0][r] *= rr;
          acc[qt][1][r] *= rr;
        }
        mq = mn;
      }
      f32x4 pA, pB;
#pragma unroll
      for (int r = 0; r < 4; r++) {
        pA[r] = exp2f(sA[r] - mq);
        pB[r] = exp2f(sB[r] - mq);
      }
      // per-lane partial denominator (wave-reduced once at the end)
      llc[qt] += pA[0] + pA[1] + pA[2] + pA[3] + pB[0] + pB[1] + pB[2] + pB[3];
      uint32_t* Pu = &PB[l15 * 20];
      Pu[2 * g]     = pkbf(pA[0], pA[1]);
      Pu[2 * g + 1] = pkbf(pA[2], pA[3]);
      Pu[8 + 2 * g]     = pkbf(pB[0], pB[1]);
      Pu[8 + 2 * g + 1] = pkbf(pB[2], pB[3]);
      uint4 pu = *(const uint4*)&PB[l15 * 20 + 4 * g];
      bf16x8 bp = __builtin_bit_cast(bf16x8, pu);
      acc[qt][0] = mfma16(bp, bv0, acc[qt][0]);
      acc[qt][1] = mfma16(bp, bv1, acc[qt][1]);
    }
  }

  // ---- reduce per-lane denominators, combine 4 wave-partials ----
#pragma unroll
  for (int qt = 0; qt < 5; qt++) {
    float t = llc[qt];
    t += __shfl_xor(t, 16, 64);
    t += __shfl_xor(t, 32, 64);
    llc[qt] = t;
  }
  __syncthreads();   // everyone done with WL/KL/VL/PB
  float* MC = (float*)arena;   // [4][2560]
#pragma unroll
  for (int qt = 0; qt < 5; qt++)
#pragma unroll
    for (int dh = 0; dh < 2; dh++)
#pragma unroll
      for (int r = 0; r < 4; r++) {
        int q = qt * 16 + 4 * g + r;
        MC[w * 2560 + q * 32 + dh * 16 + l15] = acc[qt][dh][r];
      }
  if (lane < 16) {
#pragma unroll
    for (int qt = 0; qt < 5; qt++) {
      mlS[w][qt * 16 + l15] = mlc[qt];
      mlS[w][80 + qt * 16 + l15] = llc[qt];
    }
  }
  __syncthreads();

  for (int idx = tid; idx < 2400; idx += 256) {
    int q = idx >> 5, d = idx & 31;
    float M = -1e30f;
#pragma unroll
    for (int ww = 0; ww < 4; ww++) M = fmaxf(M, mlS[ww][q]);
    float L = 0.f, O = 0.f;
#pragma unroll
    for (int ww = 0; ww < 4; ww++) {
      float sc = exp2f(mlS[ww][q] - M);
      L += mlS[ww][80 + q] * sc;
      O += MC[ww * 2560 + q * 32 + d] * sc;
    }
    obf[(size_t)(b * 75 + q) * 256 + h * 32 + d] = f2bf(O / L);
  }
}

// ---------------- host ----------------
extern "C" void kernel_launch(void* const* d_in, const int* in_sizes, int n_in,
                              void* d_out, int out_size, void* d_ws, size_t ws_size,
                              hipStream_t stream) {
  const float* x_cls   = (const float*)d_in[0];
  const float* x_patch = (const float*)d_in[1];
  const float* ln1_w   = (const float*)d_in[2];
  const float* ln1_b   = (const float*)d_in[3];
  const float* q_w     = (const float*)d_in[4];
  const float* k_w     = (const float*)d_in[5];
  const float* v_w     = (const float*)d_in[6];
  const float* proj_w  = (const float*)d_in[7];
  const float* proj_b  = (const float*)d_in[8];
  const float* ln2_w   = (const float*)d_in[9];
  const float* ln2_b   = (const float*)d_in[10];
  const float* fc1_w   = (const float*)d_in[11];
  const float* fc1_b   = (const float*)d_in[12];
  const float* fc2_w   = (const float*)d_in[13];
  const float* fc2_b   = (const float*)d_in[14];
  const float* gamma1  = (const float*)d_in[15];
  const float* gamma2  = (const float*)d_in[16];
  float* xc = (float*)d_out;

  char* ws = (char*)d_ws;
  size_t off = 0;
  auto alloc = [&](size_t bytes) {
    char* p = ws + off;
    off += (bytes + 255) & ~(size_t)255;
    return p;
  };
  u16* nxp   = (u16*)alloc(129600ull * 256 * 2);  // normalized patches (both layers)
  u16* uncls = (u16*)alloc(4800ull * 256 * 2);    // normalized cls tokens
  u16* qb    = (u16*)alloc(4800ull * 256 * 2);
  u16* ob    = (u16*)alloc(4800ull * 256 * 2);
  u16* xn    = (u16*)alloc(4800ull * 256 * 2);
  u16* hb    = (u16*)alloc(4800ull * 1024 * 2);
  u16* qp    = (u16*)alloc(2ull * 65536 * 2);
  u16* kvp   = (u16*)alloc(2ull * 131072 * 2);
  u16* pjp   = (u16*)alloc(2ull * 65536 * 2);
  u16* f1p   = (u16*)alloc(2ull * 262144 * 2);
  u16* f2p   = (u16*)alloc(2ull * 262144 * 2);
  float* bias_kv = (float*)alloc(2ull * 512 * 4);
  float* bias_q  = (float*)alloc(2ull * 256 * 4);
  float* bias_f1 = (float*)alloc(2ull * 1024 * 4);

  k_prep<<<35136, 256, 0, stream>>>(x_cls, x_patch, k_w, v_w, q_w, proj_w, fc1_w, fc2_w,
                                    ln1_w, ln1_b, ln2_w, ln2_b, fc1_b,
                                    kvp, qp, pjp, f1p, f2p,
                                    bias_kv, bias_q, bias_f1, xc, nxp);

  const float qscale = 0.25503489f;  // 1/sqrt(32) * log2(e)
  for (int i = 0; i < 2; i++) {
    k_norm<<<1200, 256, 0, stream>>>(xc, uncls, 4800);
    k_gemm6<<<150, 256, 0, stream>>>(uncls, qp + i * 65536, 256, 256, 1, 1, qscale,
                                     bias_q + i * 256, nullptr, qb, nullptr);
    k_fattn<<<512, 256, 0, stream>>>(qb, uncls, nxp, kvp + i * 131072,
                                     bias_kv + i * 512, ob);
    k_gemm6<<<150, 256, 0, stream>>>(ob, pjp + i * 65536, 256, 256, 2, 1, 0.f,
                                     proj_b + i * 256, gamma1 + i * 256, nullptr, xc);
    k_norm<<<1200, 256, 0, stream>>>(xc, xn, 4800);
    k_gemm6<<<600, 256, 0, stream>>>(xn, f1p + i * 262144, 1024, 256, 3, 3, 0.f,
                                     bias_f1 + i * 1024, nullptr, hb, nullptr);
    k_gemm6<<<150, 256, 0, stream>>>(hb, f2p + i * 262144, 256, 1024, 2, 1, 0.f,
                                     fc2_b + i * 256, gamma2 + i * 256, nullptr, xc);
  }
}

// Round 9
// 357.914 us; speedup vs baseline: 7.8385x; 1.0196x over previous
//
#include <hip/hip_runtime.h>
#include <cstdint>
#include <cstddef>

typedef unsigned short u16;
typedef float f32x4 __attribute__((ext_vector_type(4)));
typedef short s16x8 __attribute__((ext_vector_type(8)));
typedef unsigned short u16x4 __attribute__((ext_vector_type(4)));
typedef __bf16 bf16x8 __attribute__((ext_vector_type(8)));

#define DEV static __device__ __forceinline__

DEV u16 f2bf(float f) {
  uint32_t x = __float_as_uint(f);
  return (u16)((x + 0x7fffu + ((x >> 16) & 1u)) >> 16);  // RNE
}

DEV f32x4 mfma16(bf16x8 a, bf16x8 b, f32x4 c) {
  return __builtin_amdgcn_mfma_f32_16x16x32_bf16(a, b, c, 0, 0, 0);
}

DEV void mfma_bf16_asm(f32x4& acc, s16x8 a, s16x8 b) {
  asm volatile("v_mfma_f32_16x16x32_bf16 %0, %1, %2, %0" : "+v"(acc) : "v"(a), "v"(b));
}

DEV uint32_t pkbf(float lo, float hi) {
  uint32_t r;
  asm("v_cvt_pk_bf16_f32 %0, %1, %2" : "=v"(r) : "v"(lo), "v"(hi));
  return r;
}

// ---------------- mega prep: folds + casts + x_cls copy + patch norm ----------------
__global__ __launch_bounds__(256) void k_prep(
    const float* __restrict__ x_cls, const float* __restrict__ x_patch,
    const float* __restrict__ k_w, const float* __restrict__ v_w,
    const float* __restrict__ q_w, const float* __restrict__ proj_w,
    const float* __restrict__ fc1_w, const float* __restrict__ fc2_w,
    const float* __restrict__ ln1_w, const float* __restrict__ ln1_b,
    const float* __restrict__ ln2_w, const float* __restrict__ ln2_b,
    const float* __restrict__ fc1_b,
    u16* __restrict__ kvp, u16* __restrict__ qp, u16* __restrict__ pjp,
    u16* __restrict__ f1p, u16* __restrict__ f2p,
    float* __restrict__ bias_kv, float* __restrict__ bias_q, float* __restrict__ bias_f1,
    float* __restrict__ xc, u16* __restrict__ nxp) {
  const int jb = blockIdx.x;
  const int lane = threadIdx.x & 63;
  if (jb >= 2736) {
    int wv = (jb - 2736) * 4 + (threadIdx.x >> 6);
    if (wv >= 129600) return;
    float4 v = ((const float4*)(x_patch + (size_t)wv * 256))[lane];
    float s = v.x + v.y + v.z + v.w;
    float q = v.x * v.x + v.y * v.y + v.z * v.z + v.w * v.w;
#pragma unroll
    for (int m = 1; m < 64; m <<= 1) {
      s += __shfl_xor(s, m, 64);
      q += __shfl_xor(q, m, 64);
    }
    float mean = s * (1.f / 256.f);
    float var = q * (1.f / 256.f) - mean * mean;
    float rstd = rsqrtf(var + 1e-5f);
    u16x4 o;
    o[0] = f2bf((v.x - mean) * rstd);
    o[1] = f2bf((v.y - mean) * rstd);
    o[2] = f2bf((v.z - mean) * rstd);
    o[3] = f2bf((v.w - mean) * rstd);
    ((u16x4*)(nxp + (size_t)wv * 256))[lane] = o;
    return;
  }
  if (jb >= 1536) {
    int i = (jb - 1536) * 256 + threadIdx.x;
    ((float4*)xc)[i] = ((const float4*)x_cls)[i];
    return;
  }
  const int layer = jb >= 768 ? 1 : 0;
  const int j = jb - layer * 768;
  const float* W;
  const float* lw = ln1_w + layer * 256;
  const float* lb = ln1_b + layer * 256;
  const float* b0 = nullptr;
  u16* Wout;
  float* bout = nullptr;
  int rowoff;
  if (j < 64)       { W = k_w + layer * 65536;    Wout = kvp + layer * 131072;         bout = bias_kv + layer * 512;       rowoff = j * 4; }
  else if (j < 128) { W = v_w + layer * 65536;    Wout = kvp + layer * 131072 + 65536; bout = bias_kv + layer * 512 + 256; rowoff = (j - 64) * 4; }
  else if (j < 192) { W = q_w + layer * 65536;    Wout = qp + layer * 65536;           bout = bias_q + layer * 256;        rowoff = (j - 128) * 4; }
  else if (j < 448) { W = fc1_w + layer * 262144; lw = ln2_w + layer * 256; lb = ln2_b + layer * 256; b0 = fc1_b + layer * 1024;
                      Wout = f1p + layer * 262144; bout = bias_f1 + layer * 1024;      rowoff = (j - 192) * 4; }
  else if (j < 512) { W = proj_w + layer * 65536; lw = nullptr;                        Wout = pjp + layer * 65536;         rowoff = (j - 448) * 4; }
  else              { W = fc2_w + layer * 262144; lw = nullptr;                        Wout = f2p + layer * 262144;        rowoff = (j - 512) * 4; }
  const int wv = rowoff + (threadIdx.x >> 6);
  float4 w4 = ((const float4*)(W + (size_t)wv * 256))[lane];
  u16x4 o;
  if (lw) {
    float4 s4 = ((const float4*)lw)[lane];
    o[0] = f2bf(w4.x * s4.x); o[1] = f2bf(w4.y * s4.y);
    o[2] = f2bf(w4.z * s4.z); o[3] = f2bf(w4.w * s4.w);
  } else {
    o[0] = f2bf(w4.x); o[1] = f2bf(w4.y); o[2] = f2bf(w4.z); o[3] = f2bf(w4.w);
  }
  ((u16x4*)(Wout + (size_t)wv * 256))[lane] = o;
  if (bout) {
    float4 t4 = ((const float4*)lb)[lane];
    float d = w4.x * t4.x + w4.y * t4.y + w4.z * t4.z + w4.w * t4.w;
#pragma unroll
    for (int m = 1; m < 64; m <<= 1) d += __shfl_xor(d, m, 64);
    if (lane == 0) bout[wv] = (b0 ? b0[wv] : 0.f) + d;
  }
}

// ---------------- Pure normalize (affine folded into weights) ----------
__global__ __launch_bounds__(256) void k_norm(const float* __restrict__ src,
                                              u16* __restrict__ out, int ntok) {
  int wv = blockIdx.x * 4 + (threadIdx.x >> 6), lane = threadIdx.x & 63;
  if (wv >= ntok) return;
  float4 v = ((const float4*)(src + (size_t)wv * 256))[lane];
  float s = v.x + v.y + v.z + v.w;
  float q = v.x * v.x + v.y * v.y + v.z * v.z + v.w * v.w;
#pragma unroll
  for (int m = 1; m < 64; m <<= 1) {
    s += __shfl_xor(s, m, 64);
    q += __shfl_xor(q, m, 64);
  }
  float mean = s * (1.f / 256.f);
  float var = q * (1.f / 256.f) - mean * mean;
  float rstd = rsqrtf(var + 1e-5f);
  u16x4 o;
  o[0] = f2bf((v.x - mean) * rstd);
  o[1] = f2bf((v.y - mean) * rstd);
  o[2] = f2bf((v.z - mean) * rstd);
  o[3] = f2bf((v.w - mean) * rstd);
  ((u16x4*)(out + (size_t)wv * 256))[lane] = o;
}

// ---------------- small-M MFMA GEMM: 64x128 tile, BK=64 (R8-proven) ----------------
__global__ __launch_bounds__(256) void k_gemm6(const u16* __restrict__ A,
                                               const u16* __restrict__ Bw,
                                               int N, int K, int mode,
                                               int lognby, float scale,
                                               const float* __restrict__ bias,
                                               const float* __restrict__ gamma,
                                               u16* __restrict__ obf,
                                               float* __restrict__ of32) {
  __shared__ __align__(16) char smA[8192];
  __shared__ __align__(16) char smB[16384];
  const int tid = threadIdx.x, lane = tid & 63, wid = tid >> 6;
  const int wm = wid >> 1, wn = wid & 1;
  const int bid = blockIdx.x;
  const int by = bid & ((1 << lognby) - 1), bx = bid >> lognby;
  const int m0 = bx * 64, n0 = by * 128;
  const int g = lane >> 4, l15 = lane & 15;

  f32x4 acc[2][4] = {};

  for (int k0 = 0; k0 < K; k0 += 64) {
#pragma unroll
    for (int c = 0; c < 2; c++) {
      int ee = tid + 256 * c;
      int row = ee >> 3, sl = ee & 7;
      s16x8 av = *(const s16x8*)(A + (size_t)(m0 + row) * K + k0 + sl * 8);
      *(s16x8*)(smA + row * 128 + ((sl * 16) ^ ((row & 7) << 4))) = av;
    }
#pragma unroll
    for (int c = 0; c < 4; c++) {
      int ee = tid + 256 * c;
      int row = ee >> 3, sl = ee & 7;
      s16x8 bv = *(const s16x8*)(Bw + (size_t)(n0 + row) * K + k0 + sl * 8);
      *(s16x8*)(smB + row * 128 + ((sl * 16) ^ ((row & 7) << 4))) = bv;
    }
    __syncthreads();
    s16x8 af[2][2], bfr[4][2];
#pragma unroll
    for (int s = 0; s < 2; s++) {
#pragma unroll
      for (int i = 0; i < 2; i++) {
        int r = wm * 32 + i * 16 + l15;
        af[i][s] = *(const s16x8*)(smA + r * 128 + (((s * 4 + g) * 16) ^ ((r & 7) << 4)));
      }
#pragma unroll
      for (int jj = 0; jj < 4; jj++) {
        int n = wn * 64 + jj * 16 + l15;
        bfr[jj][s] = *(const s16x8*)(smB + n * 128 + (((s * 4 + g) * 16) ^ ((n & 7) << 4)));
      }
    }
#pragma unroll
    for (int s = 0; s < 2; s++)
#pragma unroll
      for (int i = 0; i < 2; i++)
#pragma unroll
        for (int jj = 0; jj < 4; jj++)
          mfma_bf16_asm(acc[i][jj], af[i][s], bfr[jj][s]);
    __syncthreads();
  }
  asm volatile("s_nop 7\n\ts_nop 7" ::: "memory");

#pragma unroll
  for (int i = 0; i < 2; i++) {
#pragma unroll
    for (int jj = 0; jj < 4; jj++) {
      int gmBase = m0 + wm * 32 + i * 16 + g * 4;
      int gn = n0 + wn * 64 + jj * 16 + l15;
      float bs = bias[gn];
#pragma unroll
      for (int r = 0; r < 4; r++) {
        int gm = gmBase + r;
        float v = acc[i][jj][r] + bs;
        if (mode == 1) {
          obf[(size_t)gm * N + gn] = f2bf(v * scale);
        } else if (mode == 2) {
          of32[(size_t)gm * N + gn] += gamma[gn] * v;
        } else {
          obf[(size_t)gm * N + gn] = f2bf(0.5f * v * (1.f + erff(v * 0.70710678118654752f)));
        }
      }
    }
  }
}

// ---------------- Fused K/V-projection + flash attention, token-split x2 ----------------
// grid 1024: b = bid&63, h = (bid>>6)&7, half = bid>>9. Each block: 33 of 66 tiles.
// R7-proven inner loop; PB overlaid on KL (LDS 52.7KB -> 3 blocks/CU).
__global__ __launch_bounds__(256, 2) void k_fattn(const u16* __restrict__ qb,
                                                  const u16* __restrict__ uncls,
                                                  const u16* __restrict__ nxp,
                                                  const u16* __restrict__ wkv,
                                                  const float* __restrict__ bias_kv,
                                                  float* __restrict__ pO,
                                                  float* __restrict__ pml) {
  __shared__ __align__(16) char arena[50176];
  __shared__ float mlS[4][160];
  const int bid = blockIdx.x;
  const int b = bid & 63, h = (bid >> 6) & 7, half = bid >> 9;
  const int tid = threadIdx.x, lane = tid & 63, w = tid >> 6;
  const int l15 = lane & 15, g = lane >> 4;
  const int tbase = half * 33, tend = tbase + 33;

  u16* WL = (u16*)arena;                      // [64][256] u16, row-xor swizzle
  char* wb = arena + 32768 + w * 4352;
  uint32_t* KL = (uint32_t*)wb;               // [32 tok][16 u32]
  uint32_t* PB = (uint32_t*)wb;               // overlay (KL consumed to regs before PB use)
  u16* VL = (u16*)(wb + 2048);                // [32 tok][36 d] u16 (padded rows)

  // ---- stage head weights (Wk rows 0..31, Wv rows 32..63) ----
  for (int it = tid; it < 2048; it += 256) {
    int row = it >> 5, c16 = it & 31;
    int srcRow = (row < 32) ? (h * 32 + row) : (256 + h * 32 + (row - 32));
    s16x8 w8 = *(const s16x8*)(wkv + (size_t)srcRow * 256 + c16 * 8);
    *(s16x8*)(WL + row * 256 + (((c16 * 16) ^ ((row & 7) << 4)) >> 1)) = w8;
  }

  float bk[2][4], bvb[2][4];
#pragma unroll
  for (int s2 = 0; s2 < 2; s2++)
#pragma unroll
    for (int r = 0; r < 4; r++) {
      bk[s2][r] = bias_kv[h * 32 + s2 * 16 + 4 * g + r];
      bvb[s2][r] = bias_kv[256 + h * 32 + s2 * 16 + 4 * g + r];
    }

  bf16x8 bq[5];
#pragma unroll
  for (int qt = 0; qt < 5; qt++) {
    int q = qt * 16 + l15; if (q > 74) q = 74;
    s16x8 qv = *(const s16x8*)(qb + (size_t)(b * 75 + q) * 256 + h * 32 + g * 8);
    bq[qt] = __builtin_bit_cast(bf16x8, qv);
  }

  f32x4 acc[5][2] = {};
  float mlc[5], llc[5];
#pragma unroll
  for (int qt = 0; qt < 5; qt++) { mlc[qt] = -1e30f; llc[qt] = 0.f; }

  __syncthreads();  // weights staged

  const int xw = (l15 & 7) << 4;   // weight-row xor
  const int xk = (l15 & 3) << 2;   // KL slot xor (R7-proven)

  for (int tt = tbase + w; tt < tend; tt += 4) {
    const int t0 = tt * 32;
    int tA = t0 + l15;      if (tA > 2099) tA = 2099;
    int tB = t0 + 16 + l15; if (tB > 2099) tB = 2099;
    const u16* rowA = (tA < 75) ? uncls + ((size_t)b * 75 + tA) * 256
                                : nxp + ((size_t)b * 2025 + (tA - 75)) * 256;
    const u16* rowB = (tB < 75) ? uncls + ((size_t)b * 75 + tB) * 256
                                : nxp + ((size_t)b * 2025 + (tB - 75)) * 256;

    // ---- project K,V: C[d][token], 8 ksteps over 256 ch ----
    f32x4 aK[2][2] = {}, aV[2][2] = {};
    __builtin_amdgcn_s_setprio(1);
#pragma unroll
    for (int ks = 0; ks < 8; ks++) {
      bf16x8 nA = __builtin_bit_cast(bf16x8, *(const s16x8*)(rowA + ks * 32 + g * 8));
      bf16x8 nB = __builtin_bit_cast(bf16x8, *(const s16x8*)(rowB + ks * 32 + g * 8));
      const int cb = (ks * 64 + g * 16) ^ xw;
      bf16x8 k0 = __builtin_bit_cast(bf16x8, *(const s16x8*)(WL + l15 * 256 + (cb >> 1)));
      bf16x8 k1 = __builtin_bit_cast(bf16x8, *(const s16x8*)(WL + (16 + l15) * 256 + (cb >> 1)));
      bf16x8 w0 = __builtin_bit_cast(bf16x8, *(const s16x8*)(WL + (32 + l15) * 256 + (cb >> 1)));
      bf16x8 w1 = __builtin_bit_cast(bf16x8, *(const s16x8*)(WL + (48 + l15) * 256 + (cb >> 1)));
      aK[0][0] = mfma16(k0, nA, aK[0][0]);
      aK[0][1] = mfma16(k0, nB, aK[0][1]);
      aK[1][0] = mfma16(k1, nA, aK[1][0]);
      aK[1][1] = mfma16(k1, nB, aK[1][1]);
      aV[0][0] = mfma16(w0, nA, aV[0][0]);
      aV[0][1] = mfma16(w0, nB, aV[0][1]);
      aV[1][0] = mfma16(w1, nA, aV[1][0]);
      aV[1][1] = mfma16(w1, nB, aV[1][1]);
    }
    __builtin_amdgcn_s_setprio(0);

    // ---- pack K/V (+bias) into per-wave LDS tiles (R7-proven layout) ----
#pragma unroll
    for (int s2 = 0; s2 < 2; s2++)
#pragma unroll
      for (int u = 0; u < 2; u++) {
        const int trow = u * 16 + l15;
        f32x4 kk4 = aK[s2][u];
        uint2 pk2;
        pk2.x = pkbf(kk4[0] + bk[s2][0], kk4[1] + bk[s2][1]);
        pk2.y = pkbf(kk4[2] + bk[s2][2], kk4[3] + bk[s2][3]);
        *(uint2*)&KL[trow * 16 + ((s2 * 8 + 2 * g) ^ ((trow & 3) << 2))] = pk2;
        f32x4 vv4 = aV[s2][u];
        uint32_t pv0 = pkbf(vv4[0] + bvb[s2][0], vv4[1] + bvb[s2][1]);
        uint32_t pv1 = pkbf(vv4[2] + bvb[s2][2], vv4[3] + bvb[s2][3]);
        *(uint32_t*)&VL[trow * 36 + s2 * 16 + 4 * g] = pv0;
        *(uint32_t*)&VL[trow * 36 + s2 * 16 + 4 * g + 2] = pv1;
      }

    // ---- K fragments ----
    uint4 ka = *(const uint4*)&KL[l15 * 16 + ((4 * g) ^ xk)];
    uint4 kb = *(const uint4*)&KL[(16 + l15) * 16 + ((4 * g) ^ xk)];
    bf16x8 bA = __builtin_bit_cast(bf16x8, ka);
    bf16x8 bB = __builtin_bit_cast(bf16x8, kb);
    // ---- V fragments ----
    s16x8 v0, v1;
#pragma unroll
    for (int e = 0; e < 8; e++) {
      v0[e] = (short)VL[(8 * g + e) * 36 + l15];
      v1[e] = (short)VL[(8 * g + e) * 36 + 16 + l15];
    }
    bf16x8 bv0 = __builtin_bit_cast(bf16x8, v0);
    bf16x8 bv1 = __builtin_bit_cast(bf16x8, v1);

    const bool lastTile = (t0 == 2080);

#pragma unroll
    for (int qt = 0; qt < 5; qt++) {
      f32x4 z = {0.f, 0.f, 0.f, 0.f};
      f32x4 sA = mfma16(bA, bq[qt], z);
      f32x4 sB = mfma16(bB, bq[qt], z);
      if (lastTile && g >= 1) {   // tokens t0+16+4g+r >= 2100
        sB[0] = sB[1] = sB[2] = sB[3] = -1e30f;
      }
      float px = fmaxf(fmaxf(fmaxf(sA[0], sA[1]), fmaxf(sA[2], sA[3])),
                       fmaxf(fmaxf(sB[0], sB[1]), fmaxf(sB[2], sB[3])));
      px = fmaxf(px, __shfl_xor(px, 16, 64));
      px = fmaxf(px, __shfl_xor(px, 32, 64));
      float mq = mlc[qt];
      if (!__all(px <= mq + 8.f)) {   // defer-max (T13)
        float mn = fmaxf(mq, px);
        float rs = exp2f(mq - mn);
        mlc[qt] = mn;
        llc[qt] *= rs;
#pragma unroll
        for (int r = 0; r < 4; r++) {
          float rr = __shfl(rs, ((lane >> 4) << 2) + r, 64);
          acc[qt][0][r] *= rr;
          acc[qt][1][r] *= rr;
        }
        mq = mn;
      }
      f32x4 pA, pB;
#pragma unroll
      for (int r = 0; r < 4; r++) {
        pA[r] = exp2f(sA[r] - mq);
        pB[r] = exp2f(sB[r] - mq);
      }
      float ps = pA[0] + pA[1] + pA[2] + pA[3] + pB[0] + pB[1] + pB[2] + pB[3];
      ps += __shfl_xor(ps, 16, 64);
      ps += __shfl_xor(ps, 32, 64);
      llc[qt] += ps;
      uint32_t* Pu = &PB[l15 * 20];
      Pu[2 * g]     = pkbf(pA[0], pA[1]);
      Pu[2 * g + 1] = pkbf(pA[2], pA[3]);
      Pu[8 + 2 * g]     = pkbf(pB[0], pB[1]);
      Pu[8 + 2 * g + 1] = pkbf(pB[2], pB[3]);
      uint4 pu = *(const uint4*)&PB[l15 * 20 + 4 * g];
      bf16x8 bp = __builtin_bit_cast(bf16x8, pu);
      acc[qt][0] = mfma16(bp, bv0, acc[qt][0]);
      acc[qt][1] = mfma16(bp, bv1, acc[qt][1]);
    }
  }

  // ---- combine 4 wave-partials, write f32 partials ----
  __syncthreads();   // everyone done with WL/KL/VL/PB
  float* MC = (float*)arena;   // [4][2560]
#pragma unroll
  for (int qt = 0; qt < 5; qt++)
#pragma unroll
    for (int dh = 0; dh < 2; dh++)
#pragma unroll
      for (int r = 0; r < 4; r++) {
        int q = qt * 16 + 4 * g + r;
        MC[w * 2560 + q * 32 + dh * 16 + l15] = acc[qt][dh][r];
      }
  if (lane < 16) {
#pragma unroll
    for (int qt = 0; qt < 5; qt++) {
      mlS[w][qt * 16 + l15] = mlc[qt];
      mlS[w][80 + qt * 16 + l15] = llc[qt];
    }
  }
  __syncthreads();

  if (tid < 75) {
    float M = -1e30f;
#pragma unroll
    for (int ww = 0; ww < 4; ww++) M = fmaxf(M, mlS[ww][tid]);
    float L = 0.f;
#pragma unroll
    for (int ww = 0; ww < 4; ww++) L += mlS[ww][80 + tid] * exp2f(mlS[ww][tid] - M);
    pml[(size_t)bid * 160 + tid] = M;
    pml[(size_t)bid * 160 + 80 + tid] = L;
  }
  for (int idx = tid; idx < 2400; idx += 256) {
    int q = idx >> 5;
    float M = -1e30f;
#pragma unroll
    for (int ww = 0; ww < 4; ww++) M = fmaxf(M, mlS[ww][q]);
    float O = 0.f;
#pragma unroll
    for (int ww = 0; ww < 4; ww++) O += MC[ww * 2560 + q * 32 + (idx & 31)] * exp2f(mlS[ww][q] - M);
    pO[(size_t)bid * 2400 + idx] = O;
  }
}

// ---------------- combine the two token-halves ----------------
__global__ __launch_bounds__(256) void k_acomb(const float* __restrict__ pO,
                                               const float* __restrict__ pml,
                                               u16* __restrict__ obf) {
  const int bid = blockIdx.x;  // 0..511 = (b,h)
  const int b = bid & 63, h = bid >> 6;
  const int tid = threadIdx.x;
  for (int idx = tid; idx < 2400; idx += 256) {
    int q = idx >> 5, d = idx & 31;
    float m0 = pml[(size_t)bid * 160 + q];
    float l0 = pml[(size_t)bid * 160 + 80 + q];
    float m1 = pml[(size_t)(bid + 512) * 160 + q];
    float l1 = pml[(size_t)(bid + 512) * 160 + 80 + q];
    float M = fmaxf(m0, m1);
    float s0 = exp2f(m0 - M), s1 = exp2f(m1 - M);
    float L = l0 * s0 + l1 * s1;
    float O = pO[(size_t)bid * 2400 + idx] * s0 + pO[(size_t)(bid + 512) * 2400 + idx] * s1;
    obf[(size_t)(b * 75 + q) * 256 + h * 32 + d] = f2bf(O / L);
  }
}

// ---------------- host ----------------
extern "C" void kernel_launch(void* const* d_in, const int* in_sizes, int n_in,
                              void* d_out, int out_size, void* d_ws, size_t ws_size,
                              hipStream_t stream) {
  const float* x_cls   = (const float*)d_in[0];
  const float* x_patch = (const float*)d_in[1];
  const float* ln1_w   = (const float*)d_in[2];
  const float* ln1_b   = (const float*)d_in[3];
  const float* q_w     = (const float*)d_in[4];
  const float* k_w     = (const float*)d_in[5];
  const float* v_w     = (const float*)d_in[6];
  const float* proj_w  = (const float*)d_in[7];
  const float* proj_b  = (const float*)d_in[8];
  const float* ln2_w   = (const float*)d_in[9];
  const float* ln2_b   = (const float*)d_in[10];
  const float* fc1_w   = (const float*)d_in[11];
  const float* fc1_b   = (const float*)d_in[12];
  const float* fc2_w   = (const float*)d_in[13];
  const float* fc2_b   = (const float*)d_in[14];
  const float* gamma1  = (const float*)d_in[15];
  const float* gamma2  = (const float*)d_in[16];
  float* xc = (float*)d_out;

  char* ws = (char*)d_ws;
  size_t off = 0;
  auto alloc = [&](size_t bytes) {
    char* p = ws + off;
    off += (bytes + 255) & ~(size_t)255;
    return p;
  };
  u16* nxp   = (u16*)alloc(129600ull * 256 * 2);
  u16* uncls = (u16*)alloc(4800ull * 256 * 2);
  u16* qb    = (u16*)alloc(4800ull * 256 * 2);
  u16* ob    = (u16*)alloc(4800ull * 256 * 2);
  u16* xn    = (u16*)alloc(4800ull * 256 * 2);
  u16* hb    = (u16*)alloc(4800ull * 1024 * 2);
  u16* qp    = (u16*)alloc(2ull * 65536 * 2);
  u16* kvp   = (u16*)alloc(2ull * 131072 * 2);
  u16* pjp   = (u16*)alloc(2ull * 65536 * 2);
  u16* f1p   = (u16*)alloc(2ull * 262144 * 2);
  u16* f2p   = (u16*)alloc(2ull * 262144 * 2);
  float* bias_kv = (float*)alloc(2ull * 512 * 4);
  float* bias_q  = (float*)alloc(2ull * 256 * 4);
  float* bias_f1 = (float*)alloc(2ull * 1024 * 4);
  float* pO  = (float*)alloc(1024ull * 2400 * 4);
  float* pml = (float*)alloc(1024ull * 160 * 4);

  k_prep<<<35136, 256, 0, stream>>>(x_cls, x_patch, k_w, v_w, q_w, proj_w, fc1_w, fc2_w,
                                    ln1_w, ln1_b, ln2_w, ln2_b, fc1_b,
                                    kvp, qp, pjp, f1p, f2p,
                                    bias_kv, bias_q, bias_f1, xc, nxp);

  const float qscale = 0.25503489f;  // 1/sqrt(32) * log2(e)
  for (int i = 0; i < 2; i++) {
    k_norm<<<1200, 256, 0, stream>>>(xc, uncls, 4800);
    k_gemm6<<<150, 256, 0, stream>>>(uncls, qp + i * 65536, 256, 256, 1, 1, qscale,
                                     bias_q + i * 256, nullptr, qb, nullptr);
    k_fattn<<<1024, 256, 0, stream>>>(qb, uncls, nxp, kvp + i * 131072,
                                      bias_kv + i * 512, pO, pml);
    k_acomb<<<512, 256, 0, stream>>>(pO, pml, ob);
    k_gemm6<<<150, 256, 0, stream>>>(ob, pjp + i * 65536, 256, 256, 2, 1, 0.f,
                                     proj_b + i * 256, gamma1 + i * 256, nullptr, xc);
    k_norm<<<1200, 256, 0, stream>>>(xc, xn, 4800);
    k_gemm6<<<600, 256, 0, stream>>>(xn, f1p + i * 262144, 1024, 256, 3, 3, 0.f,
                                     bias_f1 + i * 1024, nullptr, hb, nullptr);
    k_gemm6<<<150, 256, 0, stream>>>(hb, f2p + i * 262144, 256, 1024, 2, 1, 0.f,
                                     fc2_b + i * 256, gamma2 + i * 256, nullptr, xc);
  }
}

// Round 10
// 337.282 us; speedup vs baseline: 8.3180x; 1.0612x over previous
//
#include <hip/hip_runtime.h>
#include <cstdint>
#include <cstddef>

typedef unsigned short u16;
typedef float f32x4 __attribute__((ext_vector_type(4)));
typedef short s16x8 __attribute__((ext_vector_type(8)));
typedef unsigned short u16x4 __attribute__((ext_vector_type(4)));
typedef __bf16 bf16x8 __attribute__((ext_vector_type(8)));

#define DEV static __device__ __forceinline__

DEV u16 f2bf(float f) {
  uint32_t x = __float_as_uint(f);
  return (u16)((x + 0x7fffu + ((x >> 16) & 1u)) >> 16);  // RNE
}

DEV f32x4 mfma16(bf16x8 a, bf16x8 b, f32x4 c) {
  return __builtin_amdgcn_mfma_f32_16x16x32_bf16(a, b, c, 0, 0, 0);
}

DEV void mfma_bf16_asm(f32x4& acc, s16x8 a, s16x8 b) {
  asm volatile("v_mfma_f32_16x16x32_bf16 %0, %1, %2, %0" : "+v"(acc) : "v"(a), "v"(b));
}

DEV uint32_t pkbf(float lo, float hi) {
  uint32_t r;
  asm("v_cvt_pk_bf16_f32 %0, %1, %2" : "=v"(r) : "v"(lo), "v"(hi));
  return r;
}

// ---------------- mega prep: folds + casts + x_cls copy + patch norm ----------------
__global__ __launch_bounds__(256) void k_prep(
    const float* __restrict__ x_cls, const float* __restrict__ x_patch,
    const float* __restrict__ k_w, const float* __restrict__ v_w,
    const float* __restrict__ q_w, const float* __restrict__ proj_w,
    const float* __restrict__ fc1_w, const float* __restrict__ fc2_w,
    const float* __restrict__ ln1_w, const float* __restrict__ ln1_b,
    const float* __restrict__ ln2_w, const float* __restrict__ ln2_b,
    const float* __restrict__ fc1_b,
    u16* __restrict__ kvp, u16* __restrict__ qp, u16* __restrict__ pjp,
    u16* __restrict__ f1p, u16* __restrict__ f2p,
    float* __restrict__ bias_kv, float* __restrict__ bias_q, float* __restrict__ bias_f1,
    float* __restrict__ xc, u16* __restrict__ nxp) {
  const int jb = blockIdx.x;
  const int lane = threadIdx.x & 63;
  if (jb >= 2736) {
    int wv = (jb - 2736) * 4 + (threadIdx.x >> 6);
    if (wv >= 129600) return;
    float4 v = ((const float4*)(x_patch + (size_t)wv * 256))[lane];
    float s = v.x + v.y + v.z + v.w;
    float q = v.x * v.x + v.y * v.y + v.z * v.z + v.w * v.w;
#pragma unroll
    for (int m = 1; m < 64; m <<= 1) {
      s += __shfl_xor(s, m, 64);
      q += __shfl_xor(q, m, 64);
    }
    float mean = s * (1.f / 256.f);
    float var = q * (1.f / 256.f) - mean * mean;
    float rstd = rsqrtf(var + 1e-5f);
    u16x4 o;
    o[0] = f2bf((v.x - mean) * rstd);
    o[1] = f2bf((v.y - mean) * rstd);
    o[2] = f2bf((v.z - mean) * rstd);
    o[3] = f2bf((v.w - mean) * rstd);
    ((u16x4*)(nxp + (size_t)wv * 256))[lane] = o;
    return;
  }
  if (jb >= 1536) {
    int i = (jb - 1536) * 256 + threadIdx.x;
    ((float4*)xc)[i] = ((const float4*)x_cls)[i];
    return;
  }
  const int layer = jb >= 768 ? 1 : 0;
  const int j = jb - layer * 768;
  const float* W;
  const float* lw = ln1_w + layer * 256;
  const float* lb = ln1_b + layer * 256;
  const float* b0 = nullptr;
  u16* Wout;
  float* bout = nullptr;
  int rowoff;
  if (j < 64)       { W = k_w + layer * 65536;    Wout = kvp + layer * 131072;         bout = bias_kv + layer * 512;       rowoff = j * 4; }
  else if (j < 128) { W = v_w + layer * 65536;    Wout = kvp + layer * 131072 + 65536; bout = bias_kv + layer * 512 + 256; rowoff = (j - 64) * 4; }
  else if (j < 192) { W = q_w + layer * 65536;    Wout = qp + layer * 65536;           bout = bias_q + layer * 256;        rowoff = (j - 128) * 4; }
  else if (j < 448) { W = fc1_w + layer * 262144; lw = ln2_w + layer * 256; lb = ln2_b + layer * 256; b0 = fc1_b + layer * 1024;
                      Wout = f1p + layer * 262144; bout = bias_f1 + layer * 1024;      rowoff = (j - 192) * 4; }
  else if (j < 512) { W = proj_w + layer * 65536; lw = nullptr;                        Wout = pjp + layer * 65536;         rowoff = (j - 448) * 4; }
  else              { W = fc2_w + layer * 262144; lw = nullptr;                        Wout = f2p + layer * 262144;        rowoff = (j - 512) * 4; }
  const int wv = rowoff + (threadIdx.x >> 6);
  float4 w4 = ((const float4*)(W + (size_t)wv * 256))[lane];
  u16x4 o;
  if (lw) {
    float4 s4 = ((const float4*)lw)[lane];
    o[0] = f2bf(w4.x * s4.x); o[1] = f2bf(w4.y * s4.y);
    o[2] = f2bf(w4.z * s4.z); o[3] = f2bf(w4.w * s4.w);
  } else {
    o[0] = f2bf(w4.x); o[1] = f2bf(w4.y); o[2] = f2bf(w4.z); o[3] = f2bf(w4.w);
  }
  ((u16x4*)(Wout + (size_t)wv * 256))[lane] = o;
  if (bout) {
    float4 t4 = ((const float4*)lb)[lane];
    float d = w4.x * t4.x + w4.y * t4.y + w4.z * t4.z + w4.w * t4.w;
#pragma unroll
    for (int m = 1; m < 64; m <<= 1) d += __shfl_xor(d, m, 64);
    if (lane == 0) bout[wv] = (b0 ? b0[wv] : 0.f) + d;
  }
}

// ---------------- Pure normalize (affine folded into weights) ----------
__global__ __launch_bounds__(256) void k_norm(const float* __restrict__ src,
                                              u16* __restrict__ out, int ntok) {
  int wv = blockIdx.x * 4 + (threadIdx.x >> 6), lane = threadIdx.x & 63;
  if (wv >= ntok) return;
  float4 v = ((const float4*)(src + (size_t)wv * 256))[lane];
  float s = v.x + v.y + v.z + v.w;
  float q = v.x * v.x + v.y * v.y + v.z * v.z + v.w * v.w;
#pragma unroll
  for (int m = 1; m < 64; m <<= 1) {
    s += __shfl_xor(s, m, 64);
    q += __shfl_xor(q, m, 64);
  }
  float mean = s * (1.f / 256.f);
  float var = q * (1.f / 256.f) - mean * mean;
  float rstd = rsqrtf(var + 1e-5f);
  u16x4 o;
  o[0] = f2bf((v.x - mean) * rstd);
  o[1] = f2bf((v.y - mean) * rstd);
  o[2] = f2bf((v.z - mean) * rstd);
  o[3] = f2bf((v.w - mean) * rstd);
  ((u16x4*)(out + (size_t)wv * 256))[lane] = o;
}

// ---------------- small-M MFMA GEMM: 64x128 tile, BK=64 (R8-proven) ----------------
__global__ __launch_bounds__(256) void k_gemm6(const u16* __restrict__ A,
                                               const u16* __restrict__ Bw,
                                               int N, int K, int mode,
                                               int lognby, float scale,
                                               const float* __restrict__ bias,
                                               const float* __restrict__ gamma,
                                               u16* __restrict__ obf,
                                               float* __restrict__ of32) {
  __shared__ __align__(16) char smA[8192];
  __shared__ __align__(16) char smB[16384];
  const int tid = threadIdx.x, lane = tid & 63, wid = tid >> 6;
  const int wm = wid >> 1, wn = wid & 1;
  const int bid = blockIdx.x;
  const int by = bid & ((1 << lognby) - 1), bx = bid >> lognby;
  const int m0 = bx * 64, n0 = by * 128;
  const int g = lane >> 4, l15 = lane & 15;

  f32x4 acc[2][4] = {};

  for (int k0 = 0; k0 < K; k0 += 64) {
#pragma unroll
    for (int c = 0; c < 2; c++) {
      int ee = tid + 256 * c;
      int row = ee >> 3, sl = ee & 7;
      s16x8 av = *(const s16x8*)(A + (size_t)(m0 + row) * K + k0 + sl * 8);
      *(s16x8*)(smA + row * 128 + ((sl * 16) ^ ((row & 7) << 4))) = av;
    }
#pragma unroll
    for (int c = 0; c < 4; c++) {
      int ee = tid + 256 * c;
      int row = ee >> 3, sl = ee & 7;
      s16x8 bv = *(const s16x8*)(Bw + (size_t)(n0 + row) * K + k0 + sl * 8);
      *(s16x8*)(smB + row * 128 + ((sl * 16) ^ ((row & 7) << 4))) = bv;
    }
    __syncthreads();
    s16x8 af[2][2], bfr[4][2];
#pragma unroll
    for (int s = 0; s < 2; s++) {
#pragma unroll
      for (int i = 0; i < 2; i++) {
        int r = wm * 32 + i * 16 + l15;
        af[i][s] = *(const s16x8*)(smA + r * 128 + (((s * 4 + g) * 16) ^ ((r & 7) << 4)));
      }
#pragma unroll
      for (int jj = 0; jj < 4; jj++) {
        int n = wn * 64 + jj * 16 + l15;
        bfr[jj][s] = *(const s16x8*)(smB + n * 128 + (((s * 4 + g) * 16) ^ ((n & 7) << 4)));
      }
    }
#pragma unroll
    for (int s = 0; s < 2; s++)
#pragma unroll
      for (int i = 0; i < 2; i++)
#pragma unroll
        for (int jj = 0; jj < 4; jj++)
          mfma_bf16_asm(acc[i][jj], af[i][s], bfr[jj][s]);
    __syncthreads();
  }
  asm volatile("s_nop 7\n\ts_nop 7" ::: "memory");

#pragma unroll
  for (int i = 0; i < 2; i++) {
#pragma unroll
    for (int jj = 0; jj < 4; jj++) {
      int gmBase = m0 + wm * 32 + i * 16 + g * 4;
      int gn = n0 + wn * 64 + jj * 16 + l15;
      float bs = bias[gn];
#pragma unroll
      for (int r = 0; r < 4; r++) {
        int gm = gmBase + r;
        float v = acc[i][jj][r] + bs;
        if (mode == 1) {
          obf[(size_t)gm * N + gn] = f2bf(v * scale);
        } else if (mode == 2) {
          of32[(size_t)gm * N + gn] += gamma[gn] * v;
        } else {
          obf[(size_t)gm * N + gn] = f2bf(0.5f * v * (1.f + erff(v * 0.70710678118654752f)));
        }
      }
    }
  }
}

// ---------------- Fused K/V-projection + flash attention, token-split x2 ----------------
// grid 1024: b = bid&63, h = (bid>>6)&7, half = bid>>9. Each block: 33 of 66 tiles.
// Fixed-max softmax (P = exp2(s), no max tracking): inputs are LN'd x 0.02-scale
// weights so |S| <~ 1; exp2 domain is exact under power-of-2 scaling, f32/bf16
// ranges safe for |S| up to ~100. Removes all per-tile cross-lane reductions.
__global__ __launch_bounds__(256, 2) void k_fattn(const u16* __restrict__ qb,
                                                  const u16* __restrict__ uncls,
                                                  const u16* __restrict__ nxp,
                                                  const u16* __restrict__ wkv,
                                                  const float* __restrict__ bias_kv,
                                                  float* __restrict__ pO,
                                                  float* __restrict__ pml) {
  __shared__ __align__(16) char arena[50176];
  __shared__ float mlS[4][80];
  const int bid = blockIdx.x;
  const int b = bid & 63, h = (bid >> 6) & 7, half = bid >> 9;
  const int tid = threadIdx.x, lane = tid & 63, w = tid >> 6;
  const int l15 = lane & 15, g = lane >> 4;
  const int tbase = half * 33, tend = tbase + 33;

  u16* WL = (u16*)arena;                      // [64][256] u16, row-xor swizzle
  char* wb = arena + 32768 + w * 4352;
  uint32_t* KL = (uint32_t*)wb;               // [32 tok][16 u32]
  uint32_t* PB = (uint32_t*)wb;               // overlay (KL consumed to regs before PB use)
  u16* VL = (u16*)(wb + 2048);                // [32 tok][36 d] u16 (padded rows)

  // ---- stage head weights (Wk rows 0..31, Wv rows 32..63) ----
  for (int it = tid; it < 2048; it += 256) {
    int row = it >> 5, c16 = it & 31;
    int srcRow = (row < 32) ? (h * 32 + row) : (256 + h * 32 + (row - 32));
    s16x8 w8 = *(const s16x8*)(wkv + (size_t)srcRow * 256 + c16 * 8);
    *(s16x8*)(WL + row * 256 + (((c16 * 16) ^ ((row & 7) << 4)) >> 1)) = w8;
  }

  float bk[2][4], bvb[2][4];
#pragma unroll
  for (int s2 = 0; s2 < 2; s2++)
#pragma unroll
    for (int r = 0; r < 4; r++) {
      bk[s2][r] = bias_kv[h * 32 + s2 * 16 + 4 * g + r];
      bvb[s2][r] = bias_kv[256 + h * 32 + s2 * 16 + 4 * g + r];
    }

  bf16x8 bq[5];
#pragma unroll
  for (int qt = 0; qt < 5; qt++) {
    int q = qt * 16 + l15; if (q > 74) q = 74;
    s16x8 qv = *(const s16x8*)(qb + (size_t)(b * 75 + q) * 256 + h * 32 + g * 8);
    bq[qt] = __builtin_bit_cast(bf16x8, qv);
  }

  f32x4 acc[5][2] = {};
  float llc[5];
#pragma unroll
  for (int qt = 0; qt < 5; qt++) llc[qt] = 0.f;

  __syncthreads();  // weights staged

  const int xw = (l15 & 7) << 4;   // weight-row xor
  const int xk = (l15 & 3) << 2;   // KL slot xor (R7-proven)

  for (int tt = tbase + w; tt < tend; tt += 4) {
    const int t0 = tt * 32;
    int tA = t0 + l15;      if (tA > 2099) tA = 2099;
    int tB = t0 + 16 + l15; if (tB > 2099) tB = 2099;
    const u16* rowA = (tA < 75) ? uncls + ((size_t)b * 75 + tA) * 256
                                : nxp + ((size_t)b * 2025 + (tA - 75)) * 256;
    const u16* rowB = (tB < 75) ? uncls + ((size_t)b * 75 + tB) * 256
                                : nxp + ((size_t)b * 2025 + (tB - 75)) * 256;

    // ---- project K,V: C[d][token], 8 ksteps over 256 ch ----
    f32x4 aK[2][2] = {}, aV[2][2] = {};
    __builtin_amdgcn_s_setprio(1);
#pragma unroll
    for (int ks = 0; ks < 8; ks++) {
      bf16x8 nA = __builtin_bit_cast(bf16x8, *(const s16x8*)(rowA + ks * 32 + g * 8));
      bf16x8 nB = __builtin_bit_cast(bf16x8, *(const s16x8*)(rowB + ks * 32 + g * 8));
      const int cb = (ks * 64 + g * 16) ^ xw;
      bf16x8 k0 = __builtin_bit_cast(bf16x8, *(const s16x8*)(WL + l15 * 256 + (cb >> 1)));
      bf16x8 k1 = __builtin_bit_cast(bf16x8, *(const s16x8*)(WL + (16 + l15) * 256 + (cb >> 1)));
      bf16x8 w0 = __builtin_bit_cast(bf16x8, *(const s16x8*)(WL + (32 + l15) * 256 + (cb >> 1)));
      bf16x8 w1 = __builtin_bit_cast(bf16x8, *(const s16x8*)(WL + (48 + l15) * 256 + (cb >> 1)));
      aK[0][0] = mfma16(k0, nA, aK[0][0]);
      aK[0][1] = mfma16(k0, nB, aK[0][1]);
      aK[1][0] = mfma16(k1, nA, aK[1][0]);
      aK[1][1] = mfma16(k1, nB, aK[1][1]);
      aV[0][0] = mfma16(w0, nA, aV[0][0]);
      aV[0][1] = mfma16(w0, nB, aV[0][1]);
      aV[1][0] = mfma16(w1, nA, aV[1][0]);
      aV[1][1] = mfma16(w1, nB, aV[1][1]);
    }
    __builtin_amdgcn_s_setprio(0);

    // ---- pack K/V (+bias) into per-wave LDS tiles (R7-proven layout) ----
#pragma unroll
    for (int s2 = 0; s2 < 2; s2++)
#pragma unroll
      for (int u = 0; u < 2; u++) {
        const int trow = u * 16 + l15;
        f32x4 kk4 = aK[s2][u];
        uint2 pk2;
        pk2.x = pkbf(kk4[0] + bk[s2][0], kk4[1] + bk[s2][1]);
        pk2.y = pkbf(kk4[2] + bk[s2][2], kk4[3] + bk[s2][3]);
        *(uint2*)&KL[trow * 16 + ((s2 * 8 + 2 * g) ^ ((trow & 3) << 2))] = pk2;
        f32x4 vv4 = aV[s2][u];
        uint32_t pv0 = pkbf(vv4[0] + bvb[s2][0], vv4[1] + bvb[s2][1]);
        uint32_t pv1 = pkbf(vv4[2] + bvb[s2][2], vv4[3] + bvb[s2][3]);
        *(uint32_t*)&VL[trow * 36 + s2 * 16 + 4 * g] = pv0;
        *(uint32_t*)&VL[trow * 36 + s2 * 16 + 4 * g + 2] = pv1;
      }

    // ---- K fragments ----
    uint4 ka = *(const uint4*)&KL[l15 * 16 + ((4 * g) ^ xk)];
    uint4 kb = *(const uint4*)&KL[(16 + l15) * 16 + ((4 * g) ^ xk)];
    bf16x8 bA = __builtin_bit_cast(bf16x8, ka);
    bf16x8 bB = __builtin_bit_cast(bf16x8, kb);
    // ---- V fragments ----
    s16x8 v0, v1;
#pragma unroll
    for (int e = 0; e < 8; e++) {
      v0[e] = (short)VL[(8 * g + e) * 36 + l15];
      v1[e] = (short)VL[(8 * g + e) * 36 + 16 + l15];
    }
    bf16x8 bv0 = __builtin_bit_cast(bf16x8, v0);
    bf16x8 bv1 = __builtin_bit_cast(bf16x8, v1);

    const bool lastTile = (t0 == 2080);

#pragma unroll
    for (int qt = 0; qt < 5; qt++) {
      f32x4 z = {0.f, 0.f, 0.f, 0.f};
      f32x4 sA = mfma16(bA, bq[qt], z);
      f32x4 sB = mfma16(bB, bq[qt], z);
      if (lastTile && g >= 1) {   // tokens t0+16+4g+r >= 2100
        sB[0] = sB[1] = sB[2] = sB[3] = -1e30f;
      }
      // fixed-max softmax: P = exp2(s); denominator kept per-lane
      f32x4 pA, pB;
#pragma unroll
      for (int r = 0; r < 4; r++) {
        pA[r] = exp2f(sA[r]);
        pB[r] = exp2f(sB[r]);
      }
      llc[qt] += pA[0] + pA[1] + pA[2] + pA[3] + pB[0] + pB[1] + pB[2] + pB[3];
      uint32_t* Pu = &PB[l15 * 20];
      Pu[2 * g]     = pkbf(pA[0], pA[1]);
      Pu[2 * g + 1] = pkbf(pA[2], pA[3]);
      Pu[8 + 2 * g]     = pkbf(pB[0], pB[1]);
      Pu[8 + 2 * g + 1] = pkbf(pB[2], pB[3]);
      uint4 pu = *(const uint4*)&PB[l15 * 20 + 4 * g];
      bf16x8 bp = __builtin_bit_cast(bf16x8, pu);
      acc[qt][0] = mfma16(bp, bv0, acc[qt][0]);
      acc[qt][1] = mfma16(bp, bv1, acc[qt][1]);
    }
  }

  // ---- one-time denominator reduce; combine 4 wave-partials ----
#pragma unroll
  for (int qt = 0; qt < 5; qt++) {
    float t = llc[qt];
    t += __shfl_xor(t, 16, 64);
    t += __shfl_xor(t, 32, 64);
    llc[qt] = t;
  }
  __syncthreads();   // everyone done with WL/KL/VL/PB
  float* MC = (float*)arena;   // [4][2560]
#pragma unroll
  for (int qt = 0; qt < 5; qt++)
#pragma unroll
    for (int dh = 0; dh < 2; dh++)
#pragma unroll
      for (int r = 0; r < 4; r++) {
        int q = qt * 16 + 4 * g + r;
        MC[w * 2560 + q * 32 + dh * 16 + l15] = acc[qt][dh][r];
      }
  if (lane < 16) {
#pragma unroll
    for (int qt = 0; qt < 5; qt++) mlS[w][qt * 16 + l15] = llc[qt];
  }
  __syncthreads();

  if (tid < 75) {
    float L = mlS[0][tid] + mlS[1][tid] + mlS[2][tid] + mlS[3][tid];
    pml[(size_t)bid * 80 + tid] = L;
  }
  for (int idx = tid; idx < 2400; idx += 256) {
    int q = idx >> 5;
    float O = MC[q * 32 + (idx & 31)] + MC[2560 + q * 32 + (idx & 31)] +
              MC[5120 + q * 32 + (idx & 31)] + MC[7680 + q * 32 + (idx & 31)];
    pO[(size_t)bid * 2400 + idx] = O;
  }
}

// ---------------- combine the two token-halves ----------------
__global__ __launch_bounds__(256) void k_acomb(const float* __restrict__ pO,
                                               const float* __restrict__ pml,
                                               u16* __restrict__ obf) {
  const int bid = blockIdx.x;  // 0..511 = (b,h)
  const int b = bid & 63, h = bid >> 6;
  const int tid = threadIdx.x;
  for (int idx = tid; idx < 2400; idx += 256) {
    int q = idx >> 5, d = idx & 31;
    float L = pml[(size_t)bid * 80 + q] + pml[(size_t)(bid + 512) * 80 + q];
    float O = pO[(size_t)bid * 2400 + idx] + pO[(size_t)(bid + 512) * 2400 + idx];
    obf[(size_t)(b * 75 + q) * 256 + h * 32 + d] = f2bf(O / L);
  }
}

// ---------------- host ----------------
extern "C" void kernel_launch(void* const* d_in, const int* in_sizes, int n_in,
                              void* d_out, int out_size, void* d_ws, size_t ws_size,
                              hipStream_t stream) {
  const float* x_cls   = (const float*)d_in[0];
  const float* x_patch = (const float*)d_in[1];
  const float* ln1_w   = (const float*)d_in[2];
  const float* ln1_b   = (const float*)d_in[3];
  const float* q_w     = (const float*)d_in[4];
  const float* k_w     = (const float*)d_in[5];
  const float* v_w     = (const float*)d_in[6];
  const float* proj_w  = (const float*)d_in[7];
  const float* proj_b  = (const float*)d_in[8];
  const float* ln2_w   = (const float*)d_in[9];
  const float* ln2_b   = (const float*)d_in[10];
  const float* fc1_w   = (const float*)d_in[11];
  const float* fc1_b   = (const float*)d_in[12];
  const float* fc2_w   = (const float*)d_in[13];
  const float* fc2_b   = (const float*)d_in[14];
  const float* gamma1  = (const float*)d_in[15];
  const float* gamma2  = (const float*)d_in[16];
  float* xc = (float*)d_out;

  char* ws = (char*)d_ws;
  size_t off = 0;
  auto alloc = [&](size_t bytes) {
    char* p = ws + off;
    off += (bytes + 255) & ~(size_t)255;
    return p;
  };
  u16* nxp   = (u16*)alloc(129600ull * 256 * 2);
  u16* uncls = (u16*)alloc(4800ull * 256 * 2);
  u16* qb    = (u16*)alloc(4800ull * 256 * 2);
  u16* ob    = (u16*)alloc(4800ull * 256 * 2);
  u16* xn    = (u16*)alloc(4800ull * 256 * 2);
  u16* hb    = (u16*)alloc(4800ull * 1024 * 2);
  u16* qp    = (u16*)alloc(2ull * 65536 * 2);
  u16* kvp   = (u16*)alloc(2ull * 131072 * 2);
  u16* pjp   = (u16*)alloc(2ull * 65536 * 2);
  u16* f1p   = (u16*)alloc(2ull * 262144 * 2);
  u16* f2p   = (u16*)alloc(2ull * 262144 * 2);
  float* bias_kv = (float*)alloc(2ull * 512 * 4);
  float* bias_q  = (float*)alloc(2ull * 256 * 4);
  float* bias_f1 = (float*)alloc(2ull * 1024 * 4);
  float* pO  = (float*)alloc(1024ull * 2400 * 4);
  float* pml = (float*)alloc(1024ull * 80 * 4);

  k_prep<<<35136, 256, 0, stream>>>(x_cls, x_patch, k_w, v_w, q_w, proj_w, fc1_w, fc2_w,
                                    ln1_w, ln1_b, ln2_w, ln2_b, fc1_b,
                                    kvp, qp, pjp, f1p, f2p,
                                    bias_kv, bias_q, bias_f1, xc, nxp);

  const float qscale = 0.25503489f;  // 1/sqrt(32) * log2(e)
  for (int i = 0; i < 2; i++) {
    k_norm<<<1200, 256, 0, stream>>>(xc, uncls, 4800);
    k_gemm6<<<150, 256, 0, stream>>>(uncls, qp + i * 65536, 256, 256, 1, 1, qscale,
                                     bias_q + i * 256, nullptr, qb, nullptr);
    k_fattn<<<1024, 256, 0, stream>>>(qb, uncls, nxp, kvp + i * 131072,
                                      bias_kv + i * 512, pO, pml);
    k_acomb<<<512, 256, 0, stream>>>(pO, pml, ob);
    k_gemm6<<<150, 256, 0, stream>>>(ob, pjp + i * 65536, 256, 256, 2, 1, 0.f,
                                     proj_b + i * 256, gamma1 + i * 256, nullptr, xc);
    k_norm<<<1200, 256, 0, stream>>>(xc, xn, 4800);
    k_gemm6<<<600, 256, 0, stream>>>(xn, f1p + i * 262144, 1024, 256, 3, 3, 0.f,
                                     bias_f1 + i * 1024, nullptr, hb, nullptr);
    k_gemm6<<<150, 256, 0, stream>>>(hb, f2p + i * 262144, 256, 1024, 2, 1, 0.f,
                                     fc2_b + i * 256, gamma2 + i * 256, nullptr, xc);
  }
}